// Round 8
// baseline (411.088 us; speedup 1.0000x reference)
//
#include <hip/hip_runtime.h>
#include <hip/hip_bf16.h>

// ---------------------------------------------------------------------------
// Segment_3DCenter round 19: R16 restage structure WITHOUT the register cap.
//  - conv_mfma: single-part 36.6KB LDS buffer, stage part0 -> sync -> pass A
//    (ahi*b + alo*b) -> sync -> restage part1 -> sync -> pass B (ahi*b_lo),
//    with __launch_bounds__(512,2) (VGPR free to land ~60, NO spills).
//    LDS 36.9KB -> hardware can resident 4 blocks/CU (32 waves, full slots)
//    vs R14/R18's 2 blocks at 73KB.  R16 proved the structure correct and
//    high-occupancy; its 204us was purely spill traffic from the (512,8)
//    64-reg cap (HBM 6.7e8 bytes).  Single-variable test of the
//    latency/overlap theory of conv_mfma's 120us.
//  - Everything else identical to round 18 (sp_prep LDS-staged weights etc).
// ---------------------------------------------------------------------------

#define F_SLICE (64 * 16 * 121)          // 123904
#define PKE (64 * 121 * 134 * 16)        // u16 elements per pk plane
#define LHALF 18304                      // LDS halves per part (52*352)
#define AREP_CV 36864                    // u16 per conv in arep (36*2*64*8)
#define XPADE (64 * 121 * 136)           // u16 per xpad plane (1,053,184)

typedef _Float16 half8 __attribute__((ext_vector_type(8)));
typedef float float4v __attribute__((ext_vector_type(4)));
typedef unsigned short u16x8 __attribute__((ext_vector_type(8)));
typedef unsigned short u16x4 __attribute__((ext_vector_type(4)));

typedef __attribute__((address_space(1))) unsigned int gu32;
typedef __attribute__((address_space(3))) unsigned int lu32;

union HU { _Float16 h; unsigned short u; };

// ---------------- prep: transpose + xpad + softmax + repacks + arep --------
__global__ __launch_bounds__(256) void prep_kernel(
    const float* __restrict__ x, const float* __restrict__ cpr_w,
    const float* __restrict__ w3d1, const float* __restrict__ w2d45,
    const float* __restrict__ w3d23, float* __restrict__ x_t,
    float* __restrict__ a_sm, float* __restrict__ wrep2d,
    unsigned short* __restrict__ arep, unsigned short* __restrict__ arep1,
    unsigned short* __restrict__ xpadh, unsigned short* __restrict__ xpadl,
    unsigned short* __restrict__ zpage) {
  const int bx = blockIdx.x, t = threadIdx.x;
  if (bx < 64) {
    __shared__ float tile[128][123];
    const int b = bx;
    const float* xb = x + (size_t)b * 128 * 121;
    for (int idx = t; idx < 128 * 121; idx += 256) {
      int c = idx / 121, p = idx - c * 121;
      tile[c][p] = xb[idx];
    }
    __syncthreads();
    float* ob = x_t + (size_t)b * 121 * 128;
    for (int idx = t; idx < 121 * 128; idx += 256) {
      int p = idx >> 7, c = idx & 127;
      ob[idx] = tile[c][p];
    }
    // f16 hi/lo zero-padded planes [121][136], value = x*256
    unsigned short* xh = xpadh + (size_t)b * 16456;
    unsigned short* xl = xpadl + (size_t)b * 16456;
    for (int idx = t; idx < 16456; idx += 256) {
      int p = idx / 136, d = idx - p * 136;
      float v = 0.f;
      if (d >= 3 && d < 131) v = tile[d - 3][p] * 256.f;
      _Float16 hi = (_Float16)v;
      HU a2, b2;
      a2.h = hi;
      b2.h = (_Float16)(v - (float)hi);
      xh[idx] = a2.u;
      xl[idx] = b2.u;
    }
  } else if (bx < 112) {
    __shared__ float red[128];
    const int row = bx - 64;
    float v = (t < 128) ? cpr_w[row * 128 + t] : -3.0e38f;
    if (t < 128) red[t] = v;
    __syncthreads();
    for (int s = 64; s; s >>= 1) {
      if (t < s) red[t] = fmaxf(red[t], red[t + s]);
      __syncthreads();
    }
    float m = red[0];
    __syncthreads();
    float e = (t < 128) ? expf(v - m) : 0.f;
    if (t < 128) red[t] = e;
    __syncthreads();
    for (int s = 64; s; s >>= 1) {
      if (t < s) red[t] += red[t + s];
      __syncthreads();
    }
    if (t < 128) a_sm[row * 128 + t] = e / red[0];
  } else if (bx < 142) {
    int r = (bx - 112) * 256 + t;
    if (r < 3072) {
      // arep1[kh][part][lane][8]: k = 8q+j -> (kw=q (3+pad), kd=j (7+pad))
      int j = r & 7;
      int lane = (r >> 3) & 63;
      int part = (r >> 9) & 1;
      int kh = r >> 10;
      int m = lane & 15, q = lane >> 4;
      float w = 0.f;
      if (q < 3 && j < 7) w = w3d1[m * 63 + j * 9 + kh * 3 + q] * 256.f;
      _Float16 hi = (_Float16)w;
      HU o;
      o.h = part ? (_Float16)(w - (float)hi) : hi;
      arep1[r] = o.u;
    } else if (r < 3072 + 4608) {
      int r2 = r - 3072;
      int o = r2 & 15;
      int uv = (r2 >> 4) % 9;
      int ic = (r2 / 144) % 16;
      int layer = r2 / 2304;
      wrep2d[r2] = w2d45[((layer * 16 + o) * 16 + ic) * 9 + uv];
    }
  } else if (bx < 430) {
    int idx = (bx - 142) * 256 + t;
    if (idx < 2 * AREP_CV) {
      int j = idx & 7;
      int lane = (idx >> 3) & 63;
      int part = (idx >> 9) & 1;
      int rem = idx >> 10;
      int chunk = rem % 36;
      int cv = rem / 36;
      int kw = chunk % 3;
      int grp = chunk / 3;
      int kdp = grp & 3;
      int kh = grp >> 2;
      int m = lane & 15, q = lane >> 4;
      int kd = 2 * kdp + (q >> 1);
      int ic = (q & 1) * 8 + j;
      float w = 0.f;
      if (kd < 7)
        w = w3d23[((cv * 16 + m) * 16 + ic) * 63 + kd * 9 + kh * 3 + kw] *
            256.f;
      _Float16 hi = (_Float16)w;
      HU out;
      out.h = (part == 0) ? hi : (_Float16)(w - (float)hi);
      arep[idx] = out.u;
    }
  } else {
    // zero page for padded-panel staging loads (rewritten every launch)
    if (t < 128) {
      u16x8 z = {0, 0, 0, 0, 0, 0, 0, 0};
      *(u16x8*)&zpage[t * 8] = z;
    }
  }
}

// ---------------- conv1 via MFMA: xpad hi/lo -> pk1 planes + fpart0 --------
// grid (6 h-pairs, 4 depth-32-groups, 64 b), 512 thr = 8 waves (2 hs x 4 wg).
// K=32 per MFMA = 4 kw-slots(3 real) x 8 kd-taps(7 real); one pass per kh.
__global__ __launch_bounds__(512, 2) void conv1_mfma_kernel(
    const unsigned short* __restrict__ xph,
    const unsigned short* __restrict__ xpl,
    const unsigned short* __restrict__ arep1, const float* __restrict__ bias,
    const float* __restrict__ al, unsigned short* __restrict__ pk_hi,
    unsigned short* __restrict__ pk_lo, float* __restrict__ fpart) {
  // LDS: 104 windows (2 part x 4 row x 13 col) x 32 granules x 8 halfs
  __shared__ _Float16 lds1[104 * 256];
  const int t = threadIdx.x;
  const int bx = blockIdx.x, gy = blockIdx.y, b = blockIdx.z;
  const int lane = t & 63, wave = t >> 6;
  const int n = lane & 15, q = lane >> 4;
  const int hs = wave >> 2, wg = wave & 3;
  const int h = 2 * bx + hs;  // 0..11 (11 = dummy)
  const int D0 = gy * 32;

  // ---- staging: im2col windows, value[dloc][kd] = xpad[D0 + dloc + kd] ----
  {
    const int g = t & 31;  // dest granule (= dloc)
    const int s = g & 7;   // per-thread constant shift (halfs)
    const int w0 = t >> 5;
#pragma unroll
    for (int k = 0; k < 7; ++k) {
      int wid = w0 + k * 16;
      if (wid < 104) {
        int part = wid >= 52;
        int w2 = wid - part * 52;
        int rr = w2 / 13;
        int cc = w2 - rr * 13;
        int hh = 2 * bx - 1 + rr, ww = cc - 1;
        u16x8 v0 = {0, 0, 0, 0, 0, 0, 0, 0};
        u16x8 v1 = {0, 0, 0, 0, 0, 0, 0, 0};
        if (hh >= 0 && hh < 11 && ww >= 0 && ww < 11) {
          const unsigned short* src = (part ? xpl : xph) +
                                      ((size_t)b * 121 + hh * 11 + ww) * 136 +
                                      D0 + (g & ~7);
          v0 = *(const u16x8*)src;
          v1 = *(const u16x8*)(src + 8);
        }
        u16x8 ov;
#define SHIFT_CASE(S)                                                   \
  case S: {                                                             \
    _Pragma("unroll") for (int e = 0; e < 8; ++e) ov[e] =               \
        (((S) + e) < 8) ? v0[((S) + e) & 7] : v1[((S) + e) & 7];        \
  } break;
        switch (s) {
          SHIFT_CASE(0)
          SHIFT_CASE(1)
          SHIFT_CASE(2)
          SHIFT_CASE(3)
          SHIFT_CASE(4)
          SHIFT_CASE(5)
          SHIFT_CASE(6)
          SHIFT_CASE(7)
        }
#undef SHIFT_CASE
        *(u16x8*)&lds1[wid * 256 + g * 8] = ov;
      }
    }
  }

  // A-frags (weights) + per-lane constants
  half8 ahi[3], alo[3];
#pragma unroll
  for (int kh = 0; kh < 3; ++kh) {
    ahi[kh] = *(const half8*)&arep1[(kh * 2 + 0) * 512 + lane * 8];
    alo[kh] = *(const half8*)&arep1[(kh * 2 + 1) * 512 + lane * 8];
  }
  int colq[3];
#pragma unroll
  for (int tt = 0; tt < 3; ++tt) {
    int c = wg * 3 + tt + q;  // = (w-1+kw)+1 ; kw = q
    colq[tt] = (c > 12) ? 12 : c;  // clamp only hits zero-weight/dummy lanes
  }
  float bias_r[4];
#pragma unroll
  for (int r = 0; r < 4; ++r) bias_r[r] = bias[q * 4 + r];
  __syncthreads();

#pragma unroll
  for (int d16loc = 0; d16loc < 2; ++d16loc) {
    const int d16g = gy * 2 + d16loc;
    const int dbase = d16loc * 16 + n;  // dloc
    float4v acc[3];
#pragma unroll
    for (int tt = 0; tt < 3; ++tt) acc[tt] = (float4v){0.f, 0.f, 0.f, 0.f};
#pragma unroll
    for (int kh = 0; kh < 3; ++kh) {
      const int rowoff = (hs + kh) * 13;
#pragma unroll
      for (int tt = 0; tt < 3; ++tt) {
        const int wid = rowoff + colq[tt];
        half8 bh = *(const half8*)&lds1[wid * 256 + dbase * 8];
        half8 bl = *(const half8*)&lds1[(wid + 52) * 256 + dbase * 8];
        acc[tt] =
            __builtin_amdgcn_mfma_f32_16x16x32_f16(ahi[kh], bh, acc[tt], 0, 0, 0);
        acc[tt] =
            __builtin_amdgcn_mfma_f32_16x16x32_f16(ahi[kh], bl, acc[tt], 0, 0, 0);
        acc[tt] =
            __builtin_amdgcn_mfma_f32_16x16x32_f16(alo[kh], bh, acc[tt], 0, 0, 0);
      }
    }
    float alr[4];
#pragma unroll
    for (int r = 0; r < 4; ++r)
      alr[r] = al[(q * 4 + r) * 128 + d16g * 16 + n];
#pragma unroll
    for (int tt = 0; tt < 3; ++tt) {
      const int wl = wg * 3 + tt;
      if (h < 11 && wl < 11) {
        const int p = h * 11 + wl;
        float fr[4];
        u16x4 hi4, lo4;
#pragma unroll
        for (int r = 0; r < 4; ++r) {
          float sv = fmaxf(acc[tt][r] * (1.f / 65536.f) + bias_r[r], 0.f);
          fr[r] = sv * alr[r];
          float sc = sv * 256.f;
          _Float16 hh = (_Float16)sc;
          HU a2, b2;
          a2.h = hh;
          b2.h = (_Float16)(sc - (float)hh);
          hi4[r] = a2.u;
          lo4[r] = b2.u;
        }
        size_t base =
            (((size_t)b * 121 + p) * 134 + d16g * 16 + n + 3) * 16 + q * 4;
        *(u16x4*)&pk_hi[base] = hi4;
        *(u16x4*)&pk_lo[base] = lo4;
        u16x4 z = {0, 0, 0, 0};
        if (d16g == 0 && n < 3) {
          size_t hb = (((size_t)b * 121 + p) * 134 + n) * 16 + q * 4;
          *(u16x4*)&pk_hi[hb] = z;
          *(u16x4*)&pk_lo[hb] = z;
        }
        if (d16g == 7 && n >= 13) {
          size_t hb = (((size_t)b * 121 + p) * 134 + n + 118) * 16 + q * 4;
          *(u16x4*)&pk_hi[hb] = z;
          *(u16x4*)&pk_lo[hb] = z;
        }
        // cpr partial over this d16's 16 depths; one writer per slot
#pragma unroll
        for (int r = 0; r < 4; ++r) {
          float v = fr[r];
          v += __shfl_xor(v, 1, 64);
          v += __shfl_xor(v, 2, 64);
          v += __shfl_xor(v, 4, 64);
          v += __shfl_xor(v, 8, 64);
          if (n == 0)
            fpart[(((size_t)d16g * 64 + b) * 16 + q * 4 + r) * 121 + p] = v;
        }
      }
    }
  }
}

// ---------------- conv2/conv3: MFMA f16x2-split, 2-pass restage ------------
// Single-part LDS buffer (52 panels, [dloc][icq][ic8] conflict-free layout):
//   stage part0 -> sync -> pass A (ahi*b + alo*b, 216 MFMA)
//   -> sync -> restage part1 -> sync -> pass B (ahi*b_lo, 108 MFMA).
// 36.6 KB LDS with NO register cap (launch_bounds(512,2) -> VGPR ~60, no
// spill): hardware residency becomes LDS-limited at 4 blocks/CU (32 waves).
// cpr partials -> fpart[d16][b][oc][p] (deterministic; each slot written once)
template <bool WRITE_PK>
__global__ __launch_bounds__(512, 2) void conv_mfma_kernel(
    const unsigned short* __restrict__ pin_hi,
    const unsigned short* __restrict__ pin_lo,
    const unsigned short* __restrict__ arep, const float* __restrict__ bias,
    const float* __restrict__ al, const unsigned short* __restrict__ zpage,
    unsigned short* __restrict__ pout_hi, unsigned short* __restrict__ pout_lo,
    float* __restrict__ fpart) {
  __shared__ _Float16 lds[LHALF];
  const int t = threadIdx.x;
  const int bx = blockIdx.x, d16 = blockIdx.y, b = blockIdx.z;
  const int lane = t & 63, wave = t >> 6;
  const int n = lane & 15, q = lane >> 4;
  const int hs = wave >> 2, wg = wave & 3;
  const int h = 2 * bx + hs;  // 0..11 (11 = dummy)

  // stage one part (2288 granules of 16B) into lds
#define STAGE_PART(SRCP)                                                      \
  {                                                                           \
    _Pragma("unroll") for (int it = 0; it < 5; ++it) {                        \
      const int lbo = __builtin_amdgcn_readfirstlane((wave << 6) + it * 512); \
      const int v = lbo + lane;                                               \
      if (it < 4 || v < 2288) {                                               \
        int panel = v / 44;        /* 52 panels (4 rows x 13 cols) */         \
        int rem = v - panel * 44;  /* [dloc][icq] */                          \
        int dloc = rem >> 1;                                                  \
        int icq = rem & 1;                                                    \
        int rr = panel / 13, cc = panel - rr * 13;                            \
        int hh = 2 * bx + rr - 1, ww = cc - 1;                                \
        bool ok = (hh >= 0) & (hh < 11) & (ww >= 0) & (ww < 11);              \
        const unsigned short* g =                                             \
            ok ? &(SRCP)[(((size_t)b * 121 + hh * 11 + ww) * 134 +            \
                          d16 * 16 + dloc) * 16 + icq * 8]                    \
               : zpage;                                                       \
        __builtin_amdgcn_global_load_lds(                                     \
            (const gu32*)g, (lu32*)&lds[(size_t)lbo * 8], 16, 0, 0);          \
      }                                                                       \
    }                                                                         \
  }

  STAGE_PART(pin_hi);

  float bias_r[4], alr[4];
#pragma unroll
  for (int r = 0; r < 4; ++r) {
    bias_r[r] = bias[q * 4 + r];
    alr[r] = al[(q * 4 + r) * 128 + d16 * 16 + n];
  }

  const int wl0 = wg * 3;
  int cb[5], cbk[5];
  // [dloc][icq][8]: dloc stride = 16 halves, icq stride = 8 halves
  const int base_qn = (q & 1) * 8 + n * 16 + hs * 4576;
  const int kdh = (lane & 32) ? 16 : 0;
#pragma unroll
  for (int j = 0; j < 5; ++j) {
    int colj = wl0 + j;
    if (colj > 12) colj = 12;
    cb[j] = base_qn + colj * 352;
    cbk[j] = cb[j] + kdh;
  }

  float4v acc[3];
#pragma unroll
  for (int tt = 0; tt < 3; ++tt) acc[tt] = (float4v){0.f, 0.f, 0.f, 0.f};

  __syncthreads();

  // ---- pass A over part0: ahi*b + alo*b ----
#pragma unroll
  for (int kh = 0; kh < 3; ++kh) {
#pragma unroll
    for (int kdp = 0; kdp < 4; ++kdp) {
      half8 bf[5];
#pragma unroll
      for (int j = 0; j < 5; ++j) {
        int a = ((kdp < 3) ? cbk[j] : cb[j]) + kh * 4576 + kdp * 32;
        bf[j] = *(const half8*)&lds[a];
      }
#pragma unroll
      for (int kw = 0; kw < 3; ++kw) {
        const int c2 = (kh * 4 + kdp) * 3 + kw;
        half8 ahi = *(const half8*)&arep[((c2 * 2 + 0) * 64 + lane) * 8];
        half8 alo = *(const half8*)&arep[((c2 * 2 + 1) * 64 + lane) * 8];
#pragma unroll
        for (int tt = 0; tt < 3; ++tt) {
          const int jj = tt + kw;
          acc[tt] = __builtin_amdgcn_mfma_f32_16x16x32_f16(ahi, bf[jj],
                                                           acc[tt], 0, 0, 0);
          acc[tt] = __builtin_amdgcn_mfma_f32_16x16x32_f16(alo, bf[jj],
                                                           acc[tt], 0, 0, 0);
        }
      }
    }
  }

  __syncthreads();  // all reads of part0 complete
  STAGE_PART(pin_lo);
  __syncthreads();  // part1 visible

  // ---- pass B over part1: ahi*b_lo ----
#pragma unroll
  for (int kh = 0; kh < 3; ++kh) {
#pragma unroll
    for (int kdp = 0; kdp < 4; ++kdp) {
      half8 bf[5];
#pragma unroll
      for (int j = 0; j < 5; ++j) {
        int a = ((kdp < 3) ? cbk[j] : cb[j]) + kh * 4576 + kdp * 32;
        bf[j] = *(const half8*)&lds[a];
      }
#pragma unroll
      for (int kw = 0; kw < 3; ++kw) {
        const int c2 = (kh * 4 + kdp) * 3 + kw;
        half8 ahi = *(const half8*)&arep[((c2 * 2 + 0) * 64 + lane) * 8];
#pragma unroll
        for (int tt = 0; tt < 3; ++tt) {
          const int jj = tt + kw;
          acc[tt] = __builtin_amdgcn_mfma_f32_16x16x32_f16(ahi, bf[jj],
                                                           acc[tt], 0, 0, 0);
        }
      }
    }
  }
#undef STAGE_PART

#pragma unroll
  for (int tt = 0; tt < 3; ++tt) {
    const int wl = wg * 3 + tt;
    if (h < 11 && wl < 11) {
      const int p = h * 11 + wl;
      float fr[4];
      u16x4 hi4, lo4;
#pragma unroll
      for (int r = 0; r < 4; ++r) {
        float sv = fmaxf(acc[tt][r] * (1.f / 65536.f) + bias_r[r], 0.f);
        fr[r] = sv * alr[r];
        if (WRITE_PK) {
          float s = sv * 256.f;
          _Float16 hh = (_Float16)s;
          HU a, bb;
          a.h = hh;
          bb.h = (_Float16)(s - (float)hh);
          hi4[r] = a.u;
          lo4[r] = bb.u;
        }
      }
      if (WRITE_PK) {
        size_t base =
            (((size_t)b * 121 + p) * 134 + d16 * 16 + n + 3) * 16 + q * 4;
        *(u16x4*)&pout_hi[base] = hi4;
        *(u16x4*)&pout_lo[base] = lo4;
        u16x4 z = {0, 0, 0, 0};
        if (d16 == 0 && n < 3) {
          size_t hb = (((size_t)b * 121 + p) * 134 + n) * 16 + q * 4;
          *(u16x4*)&pout_hi[hb] = z;
          *(u16x4*)&pout_lo[hb] = z;
        }
        if (d16 == 7 && n >= 13) {
          size_t hb = (((size_t)b * 121 + p) * 134 + n + 118) * 16 + q * 4;
          *(u16x4*)&pout_hi[hb] = z;
          *(u16x4*)&pout_lo[hb] = z;
        }
      }
      // cpr partial: reduce over the 16 d's of this block; one writer per slot
#pragma unroll
      for (int r = 0; r < 4; ++r) {
        float v = fr[r];
        v += __shfl_xor(v, 1, 64);
        v += __shfl_xor(v, 2, 64);
        v += __shfl_xor(v, 4, 64);
        v += __shfl_xor(v, 8, 64);
        if (n == 0)
          fpart[(((size_t)d16 * 64 + b) * 16 + q * 4 + r) * 121 + p] = v;
      }
    }
  }
}

// ---------------- sp path (+sa side-outs, +f4/f5 recompute in LDS) ---------
// grid (64 b, 5 i), 128 thr. F source:
//   i=0: sum_d16 fpart0   i=1: sum_d16 fpart1 (fixed order)
//   i=2: sum fpart2       i=3: conv_l0(sum fpart2)
//   i=4: conv_l1(conv_l0(sum fpart2))
__global__ __launch_bounds__(128) void sp_prep_kernel(
    const float* __restrict__ fpart0, const float* __restrict__ fpart1,
    const float* __restrict__ fpart2, const float* __restrict__ x_t,
    const float* __restrict__ wrep2d, const float* __restrict__ b2d45,
    const float* __restrict__ seg_w, const float* __restrict__ seg_b,
    const float* __restrict__ so_w, const float* __restrict__ so_b,
    const float* __restrict__ sp_wa, const float* __restrict__ sp_ba,
    const float* __restrict__ sp_wb, const float* __restrict__ sp_bb,
    const float* __restrict__ sp_sw, const float* __restrict__ sp_sb,
    float* __restrict__ sa_sd, float* __restrict__ sp_sd) {
  const int b = blockIdx.x, i = blockIdx.y;
  const int t = threadIdx.x;
  __shared__ __align__(16) float fl[16 * 121];
  __shared__ __align__(16) float buf[16 * 121];
  __shared__ __align__(16) float wlds[2304];  // conv2d layer weights
  __shared__ float swlds[144];                // seg conv weights
  __shared__ float act[121];
  __shared__ float diffs[121];
  __shared__ int sel[5];
  __shared__ float s7[7], xc7[7];
  __shared__ float P[2][7][7];
  __shared__ float y1[16][9];
  __shared__ float y2[16];

  // stage seg weights (uniform broadcast reads later)
  for (int j = t; j < 144; j += 128) swlds[j] = seg_w[i * 144 + j];

  // load base feat (fixed d16 order per element -> deterministic; float4)
  {
    float* ldst = (i < 3) ? fl : buf;
    const float* fp0 = (i == 0) ? fpart0 : (i == 1) ? fpart1 : fpart2;
    const size_t boff = (size_t)b * 1936;
    for (int idx4 = t; idx4 < 484; idx4 += 128) {
      float4v s = {0.f, 0.f, 0.f, 0.f};
#pragma unroll
      for (int d16 = 0; d16 < 8; ++d16)
        s += *(const float4v*)&fp0[(size_t)d16 * F_SLICE + boff + idx4 * 4];
      float4v r;
#pragma unroll
      for (int e = 0; e < 4; ++e) r[e] = fmaxf(s[e], 0.f);
      *(float4v*)&ldst[idx4 * 4] = r;
    }
  }
  __syncthreads();

// weights read from wlds (staged per layer); bias from global (uniform)
#define CONV2D_LAYER(SRC, DST, L)                                        \
  if (t < 121) {                                                         \
    int h_ = t / 11, w_ = t - h_ * 11;                                   \
    float a_[16];                                                        \
    _Pragma("unroll") for (int o = 0; o < 16; ++o) a_[o] =               \
        b2d45[(L)*16 + o];                                               \
    for (int ic = 0; ic < 16; ++ic) {                                    \
      _Pragma("unroll") for (int u = 0; u < 3; ++u) {                    \
        int hh_ = h_ + u - 1;                                            \
        _Pragma("unroll") for (int v = 0; v < 3; ++v) {                  \
          int ww_ = w_ + v - 1;                                          \
          float val_ = (hh_ >= 0 && hh_ < 11 && ww_ >= 0 && ww_ < 11)    \
                           ? (SRC)[ic * 121 + hh_ * 11 + ww_]            \
                           : 0.f;                                        \
          const float* wp_ = wlds + (ic * 9 + u * 3 + v) * 16;           \
          float wr_[16];                                                 \
          _Pragma("unroll") for (int o = 0; o < 16; ++o) wr_[o] = wp_[o];\
          _Pragma("unroll") for (int o = 0; o < 16; ++o) a_[o] =         \
              fmaf(val_, wr_[o], a_[o]);                                 \
        }                                                                \
      }                                                                  \
    }                                                                    \
    _Pragma("unroll") for (int o = 0; o < 16; ++o)(DST)[o * 121 + t] =   \
        fmaxf(a_[o], 0.f);                                               \
  }

  if (i >= 3) {
    // stage layer-0 weights
    for (int j4 = t; j4 < 576; j4 += 128)
      *(float4v*)&wlds[j4 * 4] = *(const float4v*)&wrep2d[j4 * 4];
    __syncthreads();
    CONV2D_LAYER(buf, fl, 0)
    __syncthreads();
    if (i == 4) {
      // stage layer-1 weights (layer-0 reads done at the barrier above)
      for (int j4 = t; j4 < 576; j4 += 128)
        *(float4v*)&wlds[j4 * 4] = *(const float4v*)&wrep2d[2304 + j4 * 4];
      __syncthreads();
      CONV2D_LAYER(fl, buf, 1)
      __syncthreads();
    }
  }
  const float* F = (i == 4) ? buf : fl;

  // sa side-output for (b, i)
  if (t < 16) {
    float s = so_b[i * 16 + t];
    const float* swp = so_w + (i * 16 + t) * 16;
    for (int c = 0; c < 16; ++c) s += F[c * 121 + 60] * swp[c];
    sa_sd[((size_t)i * 64 + b) * 16 + t] = s;
  }

  // seg conv (no relu); weights from LDS broadcast
  if (t < 121) {
    int h = t / 11, w = t - h * 11;
    float a = seg_b[i];
    for (int ic = 0; ic < 16; ++ic) {
      float w9[9];
#pragma unroll
      for (int j = 0; j < 9; ++j) w9[j] = swlds[ic * 9 + j];
#pragma unroll
      for (int u = 0; u < 3; ++u) {
        int hh = h + u - 1;
#pragma unroll
        for (int v = 0; v < 3; ++v) {
          int ww = w + v - 1;
          if (hh >= 0 && hh < 11 && ww >= 0 && ww < 11)
            a = fmaf(F[ic * 121 + hh * 11 + ww], w9[u * 3 + v], a);
        }
      }
    }
    act[t] = a;
  }
  __syncthreads();
  if (t < 121) diffs[t] = fabsf(act[t] - act[60]);
  __syncthreads();

  for (int k = 0; k < 5; ++k) {
    if (t < 64) {
      float d0 = diffs[t];
      int i0 = t;
      float d1 = (t + 64 < 121) ? diffs[t + 64] : 3.0e38f;
      if (d1 < d0) { d0 = d1; i0 = t + 64; }
#pragma unroll
      for (int off = 32; off; off >>= 1) {
        float od = __shfl_down(d0, off, 64);
        int oi = __shfl_down(i0, off, 64);
        if (od < d0 || (od == d0 && oi < i0)) { d0 = od; i0 = oi; }
      }
      if (t == 0) {
        sel[k] = i0;
        diffs[i0] = 3.0e38f;
      }
    }
    __syncthreads();
  }

  if (t < 7) {
    const float* xb = x_t + (size_t)b * 121 * 128;
    float s = 0.f;
    for (int k = 0; k < 5; ++k) s += xb[(size_t)sel[k] * 128 + 61 + t];
    s7[t] = s;
    xc7[t] = xb[60 * 128 + 61 + t];
  }
  __syncthreads();
  if (t < 49) {
    int r = t / 7, c = t - r * 7;
    float d0 = s7[c];
    if (fabsf(d0) < 0.01f) d0 = 0.01f;
    float d1 = xc7[c];
    if (fabsf(d1) < 0.01f) d1 = 0.01f;
    P[0][r][c] = s7[r] / d0;
    P[1][r][c] = xc7[r] / d1;
  }
  __syncthreads();
  for (int item = t; item < 144; item += 128) {
    int ch = item / 9, pos = item - ch * 9;
    int a0 = pos / 3, b0 = pos - a0 * 3;
    float a = sp_ba[i * 16 + ch];
    const float* wa = sp_wa + ((size_t)(i * 16 + ch) * 2) * 9;
#pragma unroll
    for (int icc = 0; icc < 2; ++icc)
#pragma unroll
      for (int u = 0; u < 3; ++u)
#pragma unroll
        for (int v = 0; v < 3; ++v)
          a = fmaf(P[icc][2 * a0 + u][2 * b0 + v], wa[icc * 9 + u * 3 + v], a);
    y1[ch][pos] = fmaxf(a, 0.f);
  }
  __syncthreads();
  if (t < 16) {
    float a = sp_bb[i * 16 + t];
    const float* wb = sp_wb + (size_t)(i * 16 + t) * 16 * 9;
    for (int ch = 0; ch < 16; ++ch)
#pragma unroll
      for (int pos = 0; pos < 9; ++pos)
        a = fmaf(y1[ch][pos], wb[ch * 9 + pos], a);
    y2[t] = fmaxf(a, 0.f);
  }
  __syncthreads();
  if (t < 16) {
    float a = sp_sb[i * 16 + t];
    const float* swp = sp_sw + (size_t)(i * 16 + t) * 16;
    for (int ch = 0; ch < 16; ++ch) a = fmaf(y2[ch], swp[ch], a);
    sp_sd[((size_t)i * 64 + b) * 16 + t] = a;
  }
}

// ---------------- final fuse ------------------------------------------------
__global__ __launch_bounds__(256) void fuse_kernel(
    const float* __restrict__ sa_sd, const float* __restrict__ sp_sd,
    const float* __restrict__ fp, float* __restrict__ out) {
  int g = blockIdx.x * 256 + threadIdx.x;
  if (g >= 1024) return;
  int b = g >> 4, o = g & 15;
  float tot = 0.f;
  for (int i = 0; i < 5; ++i) {
    tot += fp[i] * sa_sd[((size_t)i * 64 + b) * 16 + o];
    tot += fp[5 + i] * sp_sd[((size_t)i * 64 + b) * 16 + o];
  }
  out[g] = tot;
}

extern "C" void kernel_launch(void* const* d_in, const int* in_sizes, int n_in,
                              void* d_out, int out_size, void* d_ws,
                              size_t ws_size, hipStream_t stream) {
  const float* x = (const float*)d_in[0];
  const float* w3d1 = (const float*)d_in[1];
  const float* b3d1 = (const float*)d_in[2];
  const float* w3d23 = (const float*)d_in[3];
  const float* b3d23 = (const float*)d_in[4];
  const float* cpr_w = (const float*)d_in[5];
  const float* w2d45 = (const float*)d_in[6];
  const float* b2d45 = (const float*)d_in[7];
  const float* seg_w = (const float*)d_in[8];
  const float* seg_b = (const float*)d_in[9];
  const float* so_w = (const float*)d_in[10];
  const float* so_b = (const float*)d_in[11];
  const float* sp_wa = (const float*)d_in[12];
  const float* sp_ba = (const float*)d_in[13];
  const float* sp_wb = (const float*)d_in[14];
  const float* sp_bb = (const float*)d_in[15];
  const float* sp_sw = (const float*)d_in[16];
  const float* sp_sb = (const float*)d_in[17];
  const float* fpar = (const float*)d_in[18];

  float* ws = (float*)d_ws;
  float* x_t = ws;                        // 991232 f
  float* a_sm = x_t + 991232;             // 6144 f
  float* fpart0 = a_sm + 6144;            // 8*F_SLICE f
  float* fpart1 = fpart0 + 8 * F_SLICE;   // 8*F_SLICE f
  float* fpart2 = fpart1 + 8 * F_SLICE;   // 8*F_SLICE f
  float* sp_sd = fpart2 + 8 * F_SLICE;    // 5120 f
  float* sa_sd = sp_sd + 5120;            // 5120 f
  float* wrep2d = sa_sd + 5120;           // 4608 f
  unsigned short* pk1h = (unsigned short*)(wrep2d + 4608);
  unsigned short* pk1l = pk1h + PKE;
  unsigned short* pk2h = pk1l + PKE;
  unsigned short* pk2l = pk2h + PKE;
  unsigned short* arep = pk2l + PKE;      // 2*AREP_CV u16
  unsigned short* arep1 = arep + 2 * AREP_CV;  // 3072 u16
  unsigned short* zpage = arep1 + 3072;   // 1024 u16 (zeroed every launch)
  // xpad planes overlay fpart1/fpart2 (prep writes, conv1_mfma reads;
  // fpart1/fpart2 are written only afterwards by conv_mfma #1/#2)
  unsigned short* xpadh = (unsigned short*)fpart1;  // XPADE u16
  unsigned short* xpadl = xpadh + XPADE;            // XPADE u16

  prep_kernel<<<431, 256, 0, stream>>>(x, cpr_w, w3d1, w2d45, w3d23, x_t,
                                       a_sm, wrep2d, arep, arep1, xpadh,
                                       xpadl, zpage);

  conv1_mfma_kernel<<<dim3(6, 4, 64), 512, 0, stream>>>(
      xpadh, xpadl, arep1, b3d1, a_sm, pk1h, pk1l, fpart0);
  conv_mfma_kernel<true><<<dim3(6, 8, 64), 512, 0, stream>>>(
      pk1h, pk1l, arep, b3d23, a_sm + 2048, zpage, pk2h, pk2l, fpart1);
  conv_mfma_kernel<false><<<dim3(6, 8, 64), 512, 0, stream>>>(
      pk2h, pk2l, arep + AREP_CV, b3d23 + 16, a_sm + 4096, zpage, nullptr,
      nullptr, fpart2);

  sp_prep_kernel<<<dim3(64, 5), 128, 0, stream>>>(
      fpart0, fpart1, fpart2, x_t, wrep2d, b2d45, seg_w, seg_b, so_w, so_b,
      sp_wa, sp_ba, sp_wb, sp_bb, sp_sw, sp_sb, sa_sd, sp_sd);
  fuse_kernel<<<4, 256, 0, stream>>>(sa_sd, sp_sd, fpar, (float*)d_out);
}

// Round 9
// 384.899 us; speedup vs baseline: 1.0680x; 1.0680x over previous
//
#include <hip/hip_runtime.h>
#include <hip/hip_bf16.h>

// ---------------------------------------------------------------------------
// Segment_3DCenter round 20:
//  - conv_mfma: R14-exact body (verified 120.5us, MfmaUtil 48%).  R15/R16/
//    R17/R19 structural interventions all regressed -> lane permanently
//    closed (2-barrier structure ceiling per m131-m141; floors MFMA 67us /
//    LDS 58us; 8-phase pipeline grid-incompatible at this tile shape).
//  - fuse_kernel folded into sp_prep: per-(b,i) atomicAdd of the weighted
//    side-outputs into d_out (order noise ~1e-6 << 6.5e-2 threshold; the
//    top-k-sensitive path is untouched).  prep zeroes d_out each launch.
//  - Everything else identical to round 18 (best verified, 379.8us).
// ---------------------------------------------------------------------------

#define F_SLICE (64 * 16 * 121)          // 123904
#define PKE (64 * 121 * 134 * 16)        // u16 elements per pk plane
#define LHALF 18304                      // LDS halves per part (52*352)
#define AREP_CV 36864                    // u16 per conv in arep (36*2*64*8)
#define XPADE (64 * 121 * 136)           // u16 per xpad plane (1,053,184)

typedef _Float16 half8 __attribute__((ext_vector_type(8)));
typedef float float4v __attribute__((ext_vector_type(4)));
typedef unsigned short u16x8 __attribute__((ext_vector_type(8)));
typedef unsigned short u16x4 __attribute__((ext_vector_type(4)));

typedef __attribute__((address_space(1))) unsigned int gu32;
typedef __attribute__((address_space(3))) unsigned int lu32;

union HU { _Float16 h; unsigned short u; };

// ---------------- prep: transpose + xpad + softmax + repacks + arep --------
__global__ __launch_bounds__(256) void prep_kernel(
    const float* __restrict__ x, const float* __restrict__ cpr_w,
    const float* __restrict__ w3d1, const float* __restrict__ w2d45,
    const float* __restrict__ w3d23, float* __restrict__ x_t,
    float* __restrict__ a_sm, float* __restrict__ wrep2d,
    unsigned short* __restrict__ arep, unsigned short* __restrict__ arep1,
    unsigned short* __restrict__ xpadh, unsigned short* __restrict__ xpadl,
    unsigned short* __restrict__ zpage, float* __restrict__ outz) {
  const int bx = blockIdx.x, t = threadIdx.x;
  if (bx < 64) {
    __shared__ float tile[128][123];
    const int b = bx;
    const float* xb = x + (size_t)b * 128 * 121;
    for (int idx = t; idx < 128 * 121; idx += 256) {
      int c = idx / 121, p = idx - c * 121;
      tile[c][p] = xb[idx];
    }
    __syncthreads();
    float* ob = x_t + (size_t)b * 121 * 128;
    for (int idx = t; idx < 121 * 128; idx += 256) {
      int p = idx >> 7, c = idx & 127;
      ob[idx] = tile[c][p];
    }
    // f16 hi/lo zero-padded planes [121][136], value = x*256
    unsigned short* xh = xpadh + (size_t)b * 16456;
    unsigned short* xl = xpadl + (size_t)b * 16456;
    for (int idx = t; idx < 16456; idx += 256) {
      int p = idx / 136, d = idx - p * 136;
      float v = 0.f;
      if (d >= 3 && d < 131) v = tile[d - 3][p] * 256.f;
      _Float16 hi = (_Float16)v;
      HU a2, b2;
      a2.h = hi;
      b2.h = (_Float16)(v - (float)hi);
      xh[idx] = a2.u;
      xl[idx] = b2.u;
    }
  } else if (bx < 112) {
    __shared__ float red[128];
    const int row = bx - 64;
    float v = (t < 128) ? cpr_w[row * 128 + t] : -3.0e38f;
    if (t < 128) red[t] = v;
    __syncthreads();
    for (int s = 64; s; s >>= 1) {
      if (t < s) red[t] = fmaxf(red[t], red[t + s]);
      __syncthreads();
    }
    float m = red[0];
    __syncthreads();
    float e = (t < 128) ? expf(v - m) : 0.f;
    if (t < 128) red[t] = e;
    __syncthreads();
    for (int s = 64; s; s >>= 1) {
      if (t < s) red[t] += red[t + s];
      __syncthreads();
    }
    if (t < 128) a_sm[row * 128 + t] = e / red[0];
  } else if (bx < 142) {
    int r = (bx - 112) * 256 + t;
    if (r < 3072) {
      // arep1[kh][part][lane][8]: k = 8q+j -> (kw=q (3+pad), kd=j (7+pad))
      int j = r & 7;
      int lane = (r >> 3) & 63;
      int part = (r >> 9) & 1;
      int kh = r >> 10;
      int m = lane & 15, q = lane >> 4;
      float w = 0.f;
      if (q < 3 && j < 7) w = w3d1[m * 63 + j * 9 + kh * 3 + q] * 256.f;
      _Float16 hi = (_Float16)w;
      HU o;
      o.h = part ? (_Float16)(w - (float)hi) : hi;
      arep1[r] = o.u;
    } else if (r < 3072 + 4608) {
      int r2 = r - 3072;
      int o = r2 & 15;
      int uv = (r2 >> 4) % 9;
      int ic = (r2 / 144) % 16;
      int layer = r2 / 2304;
      wrep2d[r2] = w2d45[((layer * 16 + o) * 16 + ic) * 9 + uv];
    }
  } else if (bx < 430) {
    int idx = (bx - 142) * 256 + t;
    if (idx < 2 * AREP_CV) {
      int j = idx & 7;
      int lane = (idx >> 3) & 63;
      int part = (idx >> 9) & 1;
      int rem = idx >> 10;
      int chunk = rem % 36;
      int cv = rem / 36;
      int kw = chunk % 3;
      int grp = chunk / 3;
      int kdp = grp & 3;
      int kh = grp >> 2;
      int m = lane & 15, q = lane >> 4;
      int kd = 2 * kdp + (q >> 1);
      int ic = (q & 1) * 8 + j;
      float w = 0.f;
      if (kd < 7)
        w = w3d23[((cv * 16 + m) * 16 + ic) * 63 + kd * 9 + kh * 3 + kw] *
            256.f;
      _Float16 hi = (_Float16)w;
      HU out;
      out.h = (part == 0) ? hi : (_Float16)(w - (float)hi);
      arep[idx] = out.u;
    }
  } else {
    // zero page for padded-panel staging loads (rewritten every launch)
    if (t < 128) {
      u16x8 z = {0, 0, 0, 0, 0, 0, 0, 0};
      *(u16x8*)&zpage[t * 8] = z;
    }
    // zero final output (sp_prep accumulates into it atomically)
    float4v zf = {0.f, 0.f, 0.f, 0.f};
    *(float4v*)&outz[t * 4] = zf;
  }
}

// ---------------- conv1 via MFMA: xpad hi/lo -> pk1 planes + fpart0 --------
// grid (6 h-pairs, 4 depth-32-groups, 64 b), 512 thr = 8 waves (2 hs x 4 wg).
// K=32 per MFMA = 4 kw-slots(3 real) x 8 kd-taps(7 real); one pass per kh.
__global__ __launch_bounds__(512, 2) void conv1_mfma_kernel(
    const unsigned short* __restrict__ xph,
    const unsigned short* __restrict__ xpl,
    const unsigned short* __restrict__ arep1, const float* __restrict__ bias,
    const float* __restrict__ al, unsigned short* __restrict__ pk_hi,
    unsigned short* __restrict__ pk_lo, float* __restrict__ fpart) {
  // LDS: 104 windows (2 part x 4 row x 13 col) x 32 granules x 8 halfs
  __shared__ _Float16 lds1[104 * 256];
  const int t = threadIdx.x;
  const int bx = blockIdx.x, gy = blockIdx.y, b = blockIdx.z;
  const int lane = t & 63, wave = t >> 6;
  const int n = lane & 15, q = lane >> 4;
  const int hs = wave >> 2, wg = wave & 3;
  const int h = 2 * bx + hs;  // 0..11 (11 = dummy)
  const int D0 = gy * 32;

  // ---- staging: im2col windows, value[dloc][kd] = xpad[D0 + dloc + kd] ----
  {
    const int g = t & 31;  // dest granule (= dloc)
    const int s = g & 7;   // per-thread constant shift (halfs)
    const int w0 = t >> 5;
#pragma unroll
    for (int k = 0; k < 7; ++k) {
      int wid = w0 + k * 16;
      if (wid < 104) {
        int part = wid >= 52;
        int w2 = wid - part * 52;
        int rr = w2 / 13;
        int cc = w2 - rr * 13;
        int hh = 2 * bx - 1 + rr, ww = cc - 1;
        u16x8 v0 = {0, 0, 0, 0, 0, 0, 0, 0};
        u16x8 v1 = {0, 0, 0, 0, 0, 0, 0, 0};
        if (hh >= 0 && hh < 11 && ww >= 0 && ww < 11) {
          const unsigned short* src = (part ? xpl : xph) +
                                      ((size_t)b * 121 + hh * 11 + ww) * 136 +
                                      D0 + (g & ~7);
          v0 = *(const u16x8*)src;
          v1 = *(const u16x8*)(src + 8);
        }
        u16x8 ov;
#define SHIFT_CASE(S)                                                   \
  case S: {                                                             \
    _Pragma("unroll") for (int e = 0; e < 8; ++e) ov[e] =               \
        (((S) + e) < 8) ? v0[((S) + e) & 7] : v1[((S) + e) & 7];        \
  } break;
        switch (s) {
          SHIFT_CASE(0)
          SHIFT_CASE(1)
          SHIFT_CASE(2)
          SHIFT_CASE(3)
          SHIFT_CASE(4)
          SHIFT_CASE(5)
          SHIFT_CASE(6)
          SHIFT_CASE(7)
        }
#undef SHIFT_CASE
        *(u16x8*)&lds1[wid * 256 + g * 8] = ov;
      }
    }
  }

  // A-frags (weights) + per-lane constants
  half8 ahi[3], alo[3];
#pragma unroll
  for (int kh = 0; kh < 3; ++kh) {
    ahi[kh] = *(const half8*)&arep1[(kh * 2 + 0) * 512 + lane * 8];
    alo[kh] = *(const half8*)&arep1[(kh * 2 + 1) * 512 + lane * 8];
  }
  int colq[3];
#pragma unroll
  for (int tt = 0; tt < 3; ++tt) {
    int c = wg * 3 + tt + q;  // = (w-1+kw)+1 ; kw = q
    colq[tt] = (c > 12) ? 12 : c;  // clamp only hits zero-weight/dummy lanes
  }
  float bias_r[4];
#pragma unroll
  for (int r = 0; r < 4; ++r) bias_r[r] = bias[q * 4 + r];
  __syncthreads();

#pragma unroll
  for (int d16loc = 0; d16loc < 2; ++d16loc) {
    const int d16g = gy * 2 + d16loc;
    const int dbase = d16loc * 16 + n;  // dloc
    float4v acc[3];
#pragma unroll
    for (int tt = 0; tt < 3; ++tt) acc[tt] = (float4v){0.f, 0.f, 0.f, 0.f};
#pragma unroll
    for (int kh = 0; kh < 3; ++kh) {
      const int rowoff = (hs + kh) * 13;
#pragma unroll
      for (int tt = 0; tt < 3; ++tt) {
        const int wid = rowoff + colq[tt];
        half8 bh = *(const half8*)&lds1[wid * 256 + dbase * 8];
        half8 bl = *(const half8*)&lds1[(wid + 52) * 256 + dbase * 8];
        acc[tt] =
            __builtin_amdgcn_mfma_f32_16x16x32_f16(ahi[kh], bh, acc[tt], 0, 0, 0);
        acc[tt] =
            __builtin_amdgcn_mfma_f32_16x16x32_f16(ahi[kh], bl, acc[tt], 0, 0, 0);
        acc[tt] =
            __builtin_amdgcn_mfma_f32_16x16x32_f16(alo[kh], bh, acc[tt], 0, 0, 0);
      }
    }
    float alr[4];
#pragma unroll
    for (int r = 0; r < 4; ++r)
      alr[r] = al[(q * 4 + r) * 128 + d16g * 16 + n];
#pragma unroll
    for (int tt = 0; tt < 3; ++tt) {
      const int wl = wg * 3 + tt;
      if (h < 11 && wl < 11) {
        const int p = h * 11 + wl;
        float fr[4];
        u16x4 hi4, lo4;
#pragma unroll
        for (int r = 0; r < 4; ++r) {
          float sv = fmaxf(acc[tt][r] * (1.f / 65536.f) + bias_r[r], 0.f);
          fr[r] = sv * alr[r];
          float sc = sv * 256.f;
          _Float16 hh = (_Float16)sc;
          HU a2, b2;
          a2.h = hh;
          b2.h = (_Float16)(sc - (float)hh);
          hi4[r] = a2.u;
          lo4[r] = b2.u;
        }
        size_t base =
            (((size_t)b * 121 + p) * 134 + d16g * 16 + n + 3) * 16 + q * 4;
        *(u16x4*)&pk_hi[base] = hi4;
        *(u16x4*)&pk_lo[base] = lo4;
        u16x4 z = {0, 0, 0, 0};
        if (d16g == 0 && n < 3) {
          size_t hb = (((size_t)b * 121 + p) * 134 + n) * 16 + q * 4;
          *(u16x4*)&pk_hi[hb] = z;
          *(u16x4*)&pk_lo[hb] = z;
        }
        if (d16g == 7 && n >= 13) {
          size_t hb = (((size_t)b * 121 + p) * 134 + n + 118) * 16 + q * 4;
          *(u16x4*)&pk_hi[hb] = z;
          *(u16x4*)&pk_lo[hb] = z;
        }
        // cpr partial over this d16's 16 depths; one writer per slot
#pragma unroll
        for (int r = 0; r < 4; ++r) {
          float v = fr[r];
          v += __shfl_xor(v, 1, 64);
          v += __shfl_xor(v, 2, 64);
          v += __shfl_xor(v, 4, 64);
          v += __shfl_xor(v, 8, 64);
          if (n == 0)
            fpart[(((size_t)d16g * 64 + b) * 16 + q * 4 + r) * 121 + p] = v;
        }
      }
    }
  }
}

// ---------------- conv2/conv3: MFMA f16x2-split, window-reuse K-loop -------
// B-tile LDS layout: [part][row][col][dloc][icq][ic8]  (icq interleaved ->
// each ds_read_b128 wave access is one contiguous window, conflict-free).
// Staging is UNIFORM global_load_lds; padded panels read the zero page.
// cpr partials -> fpart[d16][b][oc][p] (deterministic; each slot written once)
template <bool WRITE_PK>
__global__ __launch_bounds__(512, 2) void conv_mfma_kernel(
    const unsigned short* __restrict__ pin_hi,
    const unsigned short* __restrict__ pin_lo,
    const unsigned short* __restrict__ arep, const float* __restrict__ bias,
    const float* __restrict__ al, const unsigned short* __restrict__ zpage,
    unsigned short* __restrict__ pout_hi, unsigned short* __restrict__ pout_lo,
    float* __restrict__ fpart) {
  __shared__ _Float16 lds[2 * LHALF];
  const int t = threadIdx.x;
  const int bx = blockIdx.x, d16 = blockIdx.y, b = blockIdx.z;
  const int lane = t & 63, wave = t >> 6;
  const int n = lane & 15, q = lane >> 4;
  const int hs = wave >> 2, wg = wave & 3;
  const int h = 2 * bx + hs;  // 0..11 (11 = dummy)

#pragma unroll
  for (int i = 0; i < 9; ++i) {
    int u = t + i * 512;
    int lbo = __builtin_amdgcn_readfirstlane((wave << 6) + i * 512);
    if (u < 4576) {
      int part = (u >= 2288) ? 1 : 0;
      int qq = u - part * 2288;
      int panel = qq / 44;            // 52 panels (4 rows x 13 cols)
      int rem = qq - panel * 44;      // [dloc][icq]
      int dloc = rem >> 1;
      int icq = rem & 1;
      int rr = panel / 13, cc = panel - rr * 13;
      int hh = 2 * bx + rr - 1, ww = cc - 1;
      bool ok = (hh >= 0) & (hh < 11) & (ww >= 0) & (ww < 11);
      const unsigned short* srcp = part ? pin_lo : pin_hi;
      const unsigned short* g =
          ok ? &srcp[(((size_t)b * 121 + hh * 11 + ww) * 134 + d16 * 16 +
                      dloc) *
                         16 +
                     icq * 8]
             : zpage;
      __builtin_amdgcn_global_load_lds((const gu32*)g,
                                       (lu32*)&lds[(size_t)lbo * 8], 16, 0, 0);
    }
  }
  float bias_r[4], alr[4];
#pragma unroll
  for (int r = 0; r < 4; ++r) {
    bias_r[r] = bias[q * 4 + r];
    alr[r] = al[(q * 4 + r) * 128 + d16 * 16 + n];
  }
  __syncthreads();

  const int wl0 = wg * 3;
  int cb[5], cbk[5];
  // [dloc][icq][8]: dloc stride = 16 halves, icq stride = 8 halves
  const int base_qn = (q & 1) * 8 + n * 16 + hs * 4576;
  const int kdh = (lane & 32) ? 16 : 0;
#pragma unroll
  for (int j = 0; j < 5; ++j) {
    int colj = wl0 + j;
    if (colj > 12) colj = 12;
    cb[j] = base_qn + colj * 352;
    cbk[j] = cb[j] + kdh;
  }

  float4v acc[3];
#pragma unroll
  for (int tt = 0; tt < 3; ++tt) acc[tt] = (float4v){0.f, 0.f, 0.f, 0.f};

#pragma unroll
  for (int kh = 0; kh < 3; ++kh) {
#pragma unroll
    for (int kdp = 0; kdp < 4; ++kdp) {
      half8 whi[5], wlo[5];
#pragma unroll
      for (int j = 0; j < 5; ++j) {
        int a = ((kdp < 3) ? cbk[j] : cb[j]) + kh * 4576 + kdp * 32;
        whi[j] = *(const half8*)&lds[a];
        wlo[j] = *(const half8*)&lds[a + LHALF];
      }
#pragma unroll
      for (int kw = 0; kw < 3; ++kw) {
        const int c2 = (kh * 4 + kdp) * 3 + kw;
        half8 ahi = *(const half8*)&arep[((c2 * 2 + 0) * 64 + lane) * 8];
        half8 alo = *(const half8*)&arep[((c2 * 2 + 1) * 64 + lane) * 8];
#pragma unroll
        for (int tt = 0; tt < 3; ++tt) {
          const int jj = tt + kw;
          acc[tt] = __builtin_amdgcn_mfma_f32_16x16x32_f16(ahi, whi[jj],
                                                           acc[tt], 0, 0, 0);
          acc[tt] = __builtin_amdgcn_mfma_f32_16x16x32_f16(ahi, wlo[jj],
                                                           acc[tt], 0, 0, 0);
          acc[tt] = __builtin_amdgcn_mfma_f32_16x16x32_f16(alo, whi[jj],
                                                           acc[tt], 0, 0, 0);
        }
      }
    }
  }

#pragma unroll
  for (int tt = 0; tt < 3; ++tt) {
    const int wl = wg * 3 + tt;
    if (h < 11 && wl < 11) {
      const int p = h * 11 + wl;
      float fr[4];
      u16x4 hi4, lo4;
#pragma unroll
      for (int r = 0; r < 4; ++r) {
        float sv = fmaxf(acc[tt][r] * (1.f / 65536.f) + bias_r[r], 0.f);
        fr[r] = sv * alr[r];
        if (WRITE_PK) {
          float s = sv * 256.f;
          _Float16 hh = (_Float16)s;
          HU a, bb;
          a.h = hh;
          bb.h = (_Float16)(s - (float)hh);
          hi4[r] = a.u;
          lo4[r] = bb.u;
        }
      }
      if (WRITE_PK) {
        size_t base =
            (((size_t)b * 121 + p) * 134 + d16 * 16 + n + 3) * 16 + q * 4;
        *(u16x4*)&pout_hi[base] = hi4;
        *(u16x4*)&pout_lo[base] = lo4;
        u16x4 z = {0, 0, 0, 0};
        if (d16 == 0 && n < 3) {
          size_t hb = (((size_t)b * 121 + p) * 134 + n) * 16 + q * 4;
          *(u16x4*)&pout_hi[hb] = z;
          *(u16x4*)&pout_lo[hb] = z;
        }
        if (d16 == 7 && n >= 13) {
          size_t hb = (((size_t)b * 121 + p) * 134 + n + 118) * 16 + q * 4;
          *(u16x4*)&pout_hi[hb] = z;
          *(u16x4*)&pout_lo[hb] = z;
        }
      }
      // cpr partial: reduce over the 16 d's of this block; one writer per slot
#pragma unroll
      for (int r = 0; r < 4; ++r) {
        float v = fr[r];
        v += __shfl_xor(v, 1, 64);
        v += __shfl_xor(v, 2, 64);
        v += __shfl_xor(v, 4, 64);
        v += __shfl_xor(v, 8, 64);
        if (n == 0)
          fpart[(((size_t)d16 * 64 + b) * 16 + q * 4 + r) * 121 + p] = v;
      }
    }
  }
}

// ---------------- sp path (+sa side-outs, +f4/f5 recompute, +fused out) ----
// grid (64 b, 5 i), 128 thr. F source:
//   i=0: sum_d16 fpart0   i=1: sum_d16 fpart1 (fixed order)
//   i=2: sum fpart2       i=3: conv_l0(sum fpart2)
//   i=4: conv_l1(conv_l0(sum fpart2))
// Epilogue atomically accumulates fp[i]*sa + fp[5+i]*sp into out (zeroed by
// prep).  Order noise ~1e-6, far below the 6.5e-2 check threshold.
__global__ __launch_bounds__(128) void sp_prep_kernel(
    const float* __restrict__ fpart0, const float* __restrict__ fpart1,
    const float* __restrict__ fpart2, const float* __restrict__ x_t,
    const float* __restrict__ wrep2d, const float* __restrict__ b2d45,
    const float* __restrict__ seg_w, const float* __restrict__ seg_b,
    const float* __restrict__ so_w, const float* __restrict__ so_b,
    const float* __restrict__ sp_wa, const float* __restrict__ sp_ba,
    const float* __restrict__ sp_wb, const float* __restrict__ sp_bb,
    const float* __restrict__ sp_sw, const float* __restrict__ sp_sb,
    const float* __restrict__ fp, float* __restrict__ out) {
  const int b = blockIdx.x, i = blockIdx.y;
  const int t = threadIdx.x;
  __shared__ __align__(16) float fl[16 * 121];
  __shared__ __align__(16) float buf[16 * 121];
  __shared__ __align__(16) float wlds[2304];  // conv2d layer weights
  __shared__ float swlds[144];                // seg conv weights
  __shared__ float act[121];
  __shared__ float diffs[121];
  __shared__ int sel[5];
  __shared__ float s7[7], xc7[7];
  __shared__ float P[2][7][7];
  __shared__ float y1[16][9];
  __shared__ float y2[16];

  float sa_val = 0.f;  // this thread's sa side-output (t<16)

  // stage seg weights (uniform broadcast reads later)
  for (int j = t; j < 144; j += 128) swlds[j] = seg_w[i * 144 + j];

  // load base feat (fixed d16 order per element -> deterministic; float4)
  {
    float* ldst = (i < 3) ? fl : buf;
    const float* fp0 = (i == 0) ? fpart0 : (i == 1) ? fpart1 : fpart2;
    const size_t boff = (size_t)b * 1936;
    for (int idx4 = t; idx4 < 484; idx4 += 128) {
      float4v s = {0.f, 0.f, 0.f, 0.f};
#pragma unroll
      for (int d16 = 0; d16 < 8; ++d16)
        s += *(const float4v*)&fp0[(size_t)d16 * F_SLICE + boff + idx4 * 4];
      float4v r;
#pragma unroll
      for (int e = 0; e < 4; ++e) r[e] = fmaxf(s[e], 0.f);
      *(float4v*)&ldst[idx4 * 4] = r;
    }
  }
  __syncthreads();

// weights read from wlds (staged per layer); bias from global (uniform)
#define CONV2D_LAYER(SRC, DST, L)                                        \
  if (t < 121) {                                                         \
    int h_ = t / 11, w_ = t - h_ * 11;                                   \
    float a_[16];                                                        \
    _Pragma("unroll") for (int o = 0; o < 16; ++o) a_[o] =               \
        b2d45[(L)*16 + o];                                               \
    for (int ic = 0; ic < 16; ++ic) {                                    \
      _Pragma("unroll") for (int u = 0; u < 3; ++u) {                    \
        int hh_ = h_ + u - 1;                                            \
        _Pragma("unroll") for (int v = 0; v < 3; ++v) {                  \
          int ww_ = w_ + v - 1;                                          \
          float val_ = (hh_ >= 0 && hh_ < 11 && ww_ >= 0 && ww_ < 11)    \
                           ? (SRC)[ic * 121 + hh_ * 11 + ww_]            \
                           : 0.f;                                        \
          const float* wp_ = wlds + (ic * 9 + u * 3 + v) * 16;           \
          float wr_[16];                                                 \
          _Pragma("unroll") for (int o = 0; o < 16; ++o) wr_[o] = wp_[o];\
          _Pragma("unroll") for (int o = 0; o < 16; ++o) a_[o] =         \
              fmaf(val_, wr_[o], a_[o]);                                 \
        }                                                                \
      }                                                                  \
    }                                                                    \
    _Pragma("unroll") for (int o = 0; o < 16; ++o)(DST)[o * 121 + t] =   \
        fmaxf(a_[o], 0.f);                                               \
  }

  if (i >= 3) {
    // stage layer-0 weights
    for (int j4 = t; j4 < 576; j4 += 128)
      *(float4v*)&wlds[j4 * 4] = *(const float4v*)&wrep2d[j4 * 4];
    __syncthreads();
    CONV2D_LAYER(buf, fl, 0)
    __syncthreads();
    if (i == 4) {
      // stage layer-1 weights (layer-0 reads done at the barrier above)
      for (int j4 = t; j4 < 576; j4 += 128)
        *(float4v*)&wlds[j4 * 4] = *(const float4v*)&wrep2d[2304 + j4 * 4];
      __syncthreads();
      CONV2D_LAYER(fl, buf, 1)
      __syncthreads();
    }
  }
  const float* F = (i == 4) ? buf : fl;

  // sa side-output for (b, i) -> kept in register, fused at the end
  if (t < 16) {
    float s = so_b[i * 16 + t];
    const float* swp = so_w + (i * 16 + t) * 16;
    for (int c = 0; c < 16; ++c) s += F[c * 121 + 60] * swp[c];
    sa_val = s;
  }

  // seg conv (no relu); weights from LDS broadcast
  if (t < 121) {
    int h = t / 11, w = t - h * 11;
    float a = seg_b[i];
    for (int ic = 0; ic < 16; ++ic) {
      float w9[9];
#pragma unroll
      for (int j = 0; j < 9; ++j) w9[j] = swlds[ic * 9 + j];
#pragma unroll
      for (int u = 0; u < 3; ++u) {
        int hh = h + u - 1;
#pragma unroll
        for (int v = 0; v < 3; ++v) {
          int ww = w + v - 1;
          if (hh >= 0 && hh < 11 && ww >= 0 && ww < 11)
            a = fmaf(F[ic * 121 + hh * 11 + ww], w9[u * 3 + v], a);
        }
      }
    }
    act[t] = a;
  }
  __syncthreads();
  if (t < 121) diffs[t] = fabsf(act[t] - act[60]);
  __syncthreads();

  for (int k = 0; k < 5; ++k) {
    if (t < 64) {
      float d0 = diffs[t];
      int i0 = t;
      float d1 = (t + 64 < 121) ? diffs[t + 64] : 3.0e38f;
      if (d1 < d0) { d0 = d1; i0 = t + 64; }
#pragma unroll
      for (int off = 32; off; off >>= 1) {
        float od = __shfl_down(d0, off, 64);
        int oi = __shfl_down(i0, off, 64);
        if (od < d0 || (od == d0 && oi < i0)) { d0 = od; i0 = oi; }
      }
      if (t == 0) {
        sel[k] = i0;
        diffs[i0] = 3.0e38f;
      }
    }
    __syncthreads();
  }

  if (t < 7) {
    const float* xb = x_t + (size_t)b * 121 * 128;
    float s = 0.f;
    for (int k = 0; k < 5; ++k) s += xb[(size_t)sel[k] * 128 + 61 + t];
    s7[t] = s;
    xc7[t] = xb[60 * 128 + 61 + t];
  }
  __syncthreads();
  if (t < 49) {
    int r = t / 7, c = t - r * 7;
    float d0 = s7[c];
    if (fabsf(d0) < 0.01f) d0 = 0.01f;
    float d1 = xc7[c];
    if (fabsf(d1) < 0.01f) d1 = 0.01f;
    P[0][r][c] = s7[r] / d0;
    P[1][r][c] = xc7[r] / d1;
  }
  __syncthreads();
  for (int item = t; item < 144; item += 128) {
    int ch = item / 9, pos = item - ch * 9;
    int a0 = pos / 3, b0 = pos - a0 * 3;
    float a = sp_ba[i * 16 + ch];
    const float* wa = sp_wa + ((size_t)(i * 16 + ch) * 2) * 9;
#pragma unroll
    for (int icc = 0; icc < 2; ++icc)
#pragma unroll
      for (int u = 0; u < 3; ++u)
#pragma unroll
        for (int v = 0; v < 3; ++v)
          a = fmaf(P[icc][2 * a0 + u][2 * b0 + v], wa[icc * 9 + u * 3 + v], a);
    y1[ch][pos] = fmaxf(a, 0.f);
  }
  __syncthreads();
  if (t < 16) {
    float a = sp_bb[i * 16 + t];
    const float* wb = sp_wb + (size_t)(i * 16 + t) * 16 * 9;
    for (int ch = 0; ch < 16; ++ch)
#pragma unroll
      for (int pos = 0; pos < 9; ++pos)
        a = fmaf(y1[ch][pos], wb[ch * 9 + pos], a);
    y2[t] = fmaxf(a, 0.f);
  }
  __syncthreads();
  if (t < 16) {
    float a = sp_sb[i * 16 + t];
    const float* swp = sp_sw + (size_t)(i * 16 + t) * 16;
    for (int ch = 0; ch < 16; ++ch) a = fmaf(y2[ch], swp[ch], a);
    // fused final: out[b*16+t] += fp[i]*sa + fp[5+i]*sp
    atomicAdd(&out[(size_t)b * 16 + t], fp[i] * sa_val + fp[5 + i] * a);
  }
}

extern "C" void kernel_launch(void* const* d_in, const int* in_sizes, int n_in,
                              void* d_out, int out_size, void* d_ws,
                              size_t ws_size, hipStream_t stream) {
  const float* x = (const float*)d_in[0];
  const float* w3d1 = (const float*)d_in[1];
  const float* b3d1 = (const float*)d_in[2];
  const float* w3d23 = (const float*)d_in[3];
  const float* b3d23 = (const float*)d_in[4];
  const float* cpr_w = (const float*)d_in[5];
  const float* w2d45 = (const float*)d_in[6];
  const float* b2d45 = (const float*)d_in[7];
  const float* seg_w = (const float*)d_in[8];
  const float* seg_b = (const float*)d_in[9];
  const float* so_w = (const float*)d_in[10];
  const float* so_b = (const float*)d_in[11];
  const float* sp_wa = (const float*)d_in[12];
  const float* sp_ba = (const float*)d_in[13];
  const float* sp_wb = (const float*)d_in[14];
  const float* sp_bb = (const float*)d_in[15];
  const float* sp_sw = (const float*)d_in[16];
  const float* sp_sb = (const float*)d_in[17];
  const float* fpar = (const float*)d_in[18];

  float* ws = (float*)d_ws;
  float* x_t = ws;                        // 991232 f
  float* a_sm = x_t + 991232;             // 6144 f
  float* fpart0 = a_sm + 6144;            // 8*F_SLICE f
  float* fpart1 = fpart0 + 8 * F_SLICE;   // 8*F_SLICE f
  float* fpart2 = fpart1 + 8 * F_SLICE;   // 8*F_SLICE f
  float* wrep2d = fpart2 + 8 * F_SLICE;   // 4608 f
  unsigned short* pk1h = (unsigned short*)(wrep2d + 4608);
  unsigned short* pk1l = pk1h + PKE;
  unsigned short* pk2h = pk1l + PKE;
  unsigned short* pk2l = pk2h + PKE;
  unsigned short* arep = pk2l + PKE;      // 2*AREP_CV u16
  unsigned short* arep1 = arep + 2 * AREP_CV;  // 3072 u16
  unsigned short* zpage = arep1 + 3072;   // 1024 u16 (zeroed every launch)
  // xpad planes overlay fpart1/fpart2 (prep writes, conv1_mfma reads;
  // fpart1/fpart2 are written only afterwards by conv_mfma #1/#2)
  unsigned short* xpadh = (unsigned short*)fpart1;  // XPADE u16
  unsigned short* xpadl = xpadh + XPADE;            // XPADE u16

  prep_kernel<<<431, 256, 0, stream>>>(x, cpr_w, w3d1, w2d45, w3d23, x_t,
                                       a_sm, wrep2d, arep, arep1, xpadh,
                                       xpadl, zpage, (float*)d_out);

  conv1_mfma_kernel<<<dim3(6, 4, 64), 512, 0, stream>>>(
      xpadh, xpadl, arep1, b3d1, a_sm, pk1h, pk1l, fpart0);
  conv_mfma_kernel<true><<<dim3(6, 8, 64), 512, 0, stream>>>(
      pk1h, pk1l, arep, b3d23, a_sm + 2048, zpage, pk2h, pk2l, fpart1);
  conv_mfma_kernel<false><<<dim3(6, 8, 64), 512, 0, stream>>>(
      pk2h, pk2l, arep + AREP_CV, b3d23 + 16, a_sm + 4096, zpage, nullptr,
      nullptr, fpart2);

  sp_prep_kernel<<<dim3(64, 5), 128, 0, stream>>>(
      fpart0, fpart1, fpart2, x_t, wrep2d, b2d45, seg_w, seg_b, so_w, so_b,
      sp_wa, sp_ba, sp_wb, sp_bb, sp_sw, sp_sb, fpar, (float*)d_out);
}

// Round 10
// 375.102 us; speedup vs baseline: 1.0959x; 1.0261x over previous
//
#include <hip/hip_runtime.h>
#include <hip/hip_bf16.h>

// ---------------------------------------------------------------------------
// Segment_3DCenter round 21:
//  - Reverted R20's fuse-fold (atomics cost +5us vs separate fuse): back to
//    R18 structure (best verified, 379.8us).
//  - sp_prep: block 128 -> 256 threads; CONV2D_LAYER split 2 threads per
//    position x 8 output channels each (per-oc accumulation order unchanged
//    -> bit-identical F).  Halves the serial fmaf+LDS chain of the i>=3
//    blocks and doubles waves/CU (2.5 -> 5).  Seg-conv (feeds top-k) is
//    byte-identical.  Single-variable change on top of R18.
//  - conv_mfma: R14-exact (closed lane, 120.5us/dispatch verified 5x).
// ---------------------------------------------------------------------------

#define F_SLICE (64 * 16 * 121)          // 123904
#define PKE (64 * 121 * 134 * 16)        // u16 elements per pk plane
#define LHALF 18304                      // LDS halves per part (52*352)
#define AREP_CV 36864                    // u16 per conv in arep (36*2*64*8)
#define XPADE (64 * 121 * 136)           // u16 per xpad plane (1,053,184)

typedef _Float16 half8 __attribute__((ext_vector_type(8)));
typedef float float4v __attribute__((ext_vector_type(4)));
typedef unsigned short u16x8 __attribute__((ext_vector_type(8)));
typedef unsigned short u16x4 __attribute__((ext_vector_type(4)));

typedef __attribute__((address_space(1))) unsigned int gu32;
typedef __attribute__((address_space(3))) unsigned int lu32;

union HU { _Float16 h; unsigned short u; };

// ---------------- prep: transpose + xpad + softmax + repacks + arep --------
__global__ __launch_bounds__(256) void prep_kernel(
    const float* __restrict__ x, const float* __restrict__ cpr_w,
    const float* __restrict__ w3d1, const float* __restrict__ w2d45,
    const float* __restrict__ w3d23, float* __restrict__ x_t,
    float* __restrict__ a_sm, float* __restrict__ wrep2d,
    unsigned short* __restrict__ arep, unsigned short* __restrict__ arep1,
    unsigned short* __restrict__ xpadh, unsigned short* __restrict__ xpadl,
    unsigned short* __restrict__ zpage) {
  const int bx = blockIdx.x, t = threadIdx.x;
  if (bx < 64) {
    __shared__ float tile[128][123];
    const int b = bx;
    const float* xb = x + (size_t)b * 128 * 121;
    for (int idx = t; idx < 128 * 121; idx += 256) {
      int c = idx / 121, p = idx - c * 121;
      tile[c][p] = xb[idx];
    }
    __syncthreads();
    float* ob = x_t + (size_t)b * 121 * 128;
    for (int idx = t; idx < 121 * 128; idx += 256) {
      int p = idx >> 7, c = idx & 127;
      ob[idx] = tile[c][p];
    }
    // f16 hi/lo zero-padded planes [121][136], value = x*256
    unsigned short* xh = xpadh + (size_t)b * 16456;
    unsigned short* xl = xpadl + (size_t)b * 16456;
    for (int idx = t; idx < 16456; idx += 256) {
      int p = idx / 136, d = idx - p * 136;
      float v = 0.f;
      if (d >= 3 && d < 131) v = tile[d - 3][p] * 256.f;
      _Float16 hi = (_Float16)v;
      HU a2, b2;
      a2.h = hi;
      b2.h = (_Float16)(v - (float)hi);
      xh[idx] = a2.u;
      xl[idx] = b2.u;
    }
  } else if (bx < 112) {
    __shared__ float red[128];
    const int row = bx - 64;
    float v = (t < 128) ? cpr_w[row * 128 + t] : -3.0e38f;
    if (t < 128) red[t] = v;
    __syncthreads();
    for (int s = 64; s; s >>= 1) {
      if (t < s) red[t] = fmaxf(red[t], red[t + s]);
      __syncthreads();
    }
    float m = red[0];
    __syncthreads();
    float e = (t < 128) ? expf(v - m) : 0.f;
    if (t < 128) red[t] = e;
    __syncthreads();
    for (int s = 64; s; s >>= 1) {
      if (t < s) red[t] += red[t + s];
      __syncthreads();
    }
    if (t < 128) a_sm[row * 128 + t] = e / red[0];
  } else if (bx < 142) {
    int r = (bx - 112) * 256 + t;
    if (r < 3072) {
      // arep1[kh][part][lane][8]: k = 8q+j -> (kw=q (3+pad), kd=j (7+pad))
      int j = r & 7;
      int lane = (r >> 3) & 63;
      int part = (r >> 9) & 1;
      int kh = r >> 10;
      int m = lane & 15, q = lane >> 4;
      float w = 0.f;
      if (q < 3 && j < 7) w = w3d1[m * 63 + j * 9 + kh * 3 + q] * 256.f;
      _Float16 hi = (_Float16)w;
      HU o;
      o.h = part ? (_Float16)(w - (float)hi) : hi;
      arep1[r] = o.u;
    } else if (r < 3072 + 4608) {
      int r2 = r - 3072;
      int o = r2 & 15;
      int uv = (r2 >> 4) % 9;
      int ic = (r2 / 144) % 16;
      int layer = r2 / 2304;
      wrep2d[r2] = w2d45[((layer * 16 + o) * 16 + ic) * 9 + uv];
    }
  } else if (bx < 430) {
    int idx = (bx - 142) * 256 + t;
    if (idx < 2 * AREP_CV) {
      int j = idx & 7;
      int lane = (idx >> 3) & 63;
      int part = (idx >> 9) & 1;
      int rem = idx >> 10;
      int chunk = rem % 36;
      int cv = rem / 36;
      int kw = chunk % 3;
      int grp = chunk / 3;
      int kdp = grp & 3;
      int kh = grp >> 2;
      int m = lane & 15, q = lane >> 4;
      int kd = 2 * kdp + (q >> 1);
      int ic = (q & 1) * 8 + j;
      float w = 0.f;
      if (kd < 7)
        w = w3d23[((cv * 16 + m) * 16 + ic) * 63 + kd * 9 + kh * 3 + kw] *
            256.f;
      _Float16 hi = (_Float16)w;
      HU out;
      out.h = (part == 0) ? hi : (_Float16)(w - (float)hi);
      arep[idx] = out.u;
    }
  } else {
    // zero page for padded-panel staging loads (rewritten every launch)
    if (t < 128) {
      u16x8 z = {0, 0, 0, 0, 0, 0, 0, 0};
      *(u16x8*)&zpage[t * 8] = z;
    }
  }
}

// ---------------- conv1 via MFMA: xpad hi/lo -> pk1 planes + fpart0 --------
// grid (6 h-pairs, 4 depth-32-groups, 64 b), 512 thr = 8 waves (2 hs x 4 wg).
// K=32 per MFMA = 4 kw-slots(3 real) x 8 kd-taps(7 real); one pass per kh.
__global__ __launch_bounds__(512, 2) void conv1_mfma_kernel(
    const unsigned short* __restrict__ xph,
    const unsigned short* __restrict__ xpl,
    const unsigned short* __restrict__ arep1, const float* __restrict__ bias,
    const float* __restrict__ al, unsigned short* __restrict__ pk_hi,
    unsigned short* __restrict__ pk_lo, float* __restrict__ fpart) {
  // LDS: 104 windows (2 part x 4 row x 13 col) x 32 granules x 8 halfs
  __shared__ _Float16 lds1[104 * 256];
  const int t = threadIdx.x;
  const int bx = blockIdx.x, gy = blockIdx.y, b = blockIdx.z;
  const int lane = t & 63, wave = t >> 6;
  const int n = lane & 15, q = lane >> 4;
  const int hs = wave >> 2, wg = wave & 3;
  const int h = 2 * bx + hs;  // 0..11 (11 = dummy)
  const int D0 = gy * 32;

  // ---- staging: im2col windows, value[dloc][kd] = xpad[D0 + dloc + kd] ----
  {
    const int g = t & 31;  // dest granule (= dloc)
    const int s = g & 7;   // per-thread constant shift (halfs)
    const int w0 = t >> 5;
#pragma unroll
    for (int k = 0; k < 7; ++k) {
      int wid = w0 + k * 16;
      if (wid < 104) {
        int part = wid >= 52;
        int w2 = wid - part * 52;
        int rr = w2 / 13;
        int cc = w2 - rr * 13;
        int hh = 2 * bx - 1 + rr, ww = cc - 1;
        u16x8 v0 = {0, 0, 0, 0, 0, 0, 0, 0};
        u16x8 v1 = {0, 0, 0, 0, 0, 0, 0, 0};
        if (hh >= 0 && hh < 11 && ww >= 0 && ww < 11) {
          const unsigned short* src = (part ? xpl : xph) +
                                      ((size_t)b * 121 + hh * 11 + ww) * 136 +
                                      D0 + (g & ~7);
          v0 = *(const u16x8*)src;
          v1 = *(const u16x8*)(src + 8);
        }
        u16x8 ov;
#define SHIFT_CASE(S)                                                   \
  case S: {                                                             \
    _Pragma("unroll") for (int e = 0; e < 8; ++e) ov[e] =               \
        (((S) + e) < 8) ? v0[((S) + e) & 7] : v1[((S) + e) & 7];        \
  } break;
        switch (s) {
          SHIFT_CASE(0)
          SHIFT_CASE(1)
          SHIFT_CASE(2)
          SHIFT_CASE(3)
          SHIFT_CASE(4)
          SHIFT_CASE(5)
          SHIFT_CASE(6)
          SHIFT_CASE(7)
        }
#undef SHIFT_CASE
        *(u16x8*)&lds1[wid * 256 + g * 8] = ov;
      }
    }
  }

  // A-frags (weights) + per-lane constants
  half8 ahi[3], alo[3];
#pragma unroll
  for (int kh = 0; kh < 3; ++kh) {
    ahi[kh] = *(const half8*)&arep1[(kh * 2 + 0) * 512 + lane * 8];
    alo[kh] = *(const half8*)&arep1[(kh * 2 + 1) * 512 + lane * 8];
  }
  int colq[3];
#pragma unroll
  for (int tt = 0; tt < 3; ++tt) {
    int c = wg * 3 + tt + q;  // = (w-1+kw)+1 ; kw = q
    colq[tt] = (c > 12) ? 12 : c;  // clamp only hits zero-weight/dummy lanes
  }
  float bias_r[4];
#pragma unroll
  for (int r = 0; r < 4; ++r) bias_r[r] = bias[q * 4 + r];
  __syncthreads();

#pragma unroll
  for (int d16loc = 0; d16loc < 2; ++d16loc) {
    const int d16g = gy * 2 + d16loc;
    const int dbase = d16loc * 16 + n;  // dloc
    float4v acc[3];
#pragma unroll
    for (int tt = 0; tt < 3; ++tt) acc[tt] = (float4v){0.f, 0.f, 0.f, 0.f};
#pragma unroll
    for (int kh = 0; kh < 3; ++kh) {
      const int rowoff = (hs + kh) * 13;
#pragma unroll
      for (int tt = 0; tt < 3; ++tt) {
        const int wid = rowoff + colq[tt];
        half8 bh = *(const half8*)&lds1[wid * 256 + dbase * 8];
        half8 bl = *(const half8*)&lds1[(wid + 52) * 256 + dbase * 8];
        acc[tt] =
            __builtin_amdgcn_mfma_f32_16x16x32_f16(ahi[kh], bh, acc[tt], 0, 0, 0);
        acc[tt] =
            __builtin_amdgcn_mfma_f32_16x16x32_f16(ahi[kh], bl, acc[tt], 0, 0, 0);
        acc[tt] =
            __builtin_amdgcn_mfma_f32_16x16x32_f16(alo[kh], bh, acc[tt], 0, 0, 0);
      }
    }
    float alr[4];
#pragma unroll
    for (int r = 0; r < 4; ++r)
      alr[r] = al[(q * 4 + r) * 128 + d16g * 16 + n];
#pragma unroll
    for (int tt = 0; tt < 3; ++tt) {
      const int wl = wg * 3 + tt;
      if (h < 11 && wl < 11) {
        const int p = h * 11 + wl;
        float fr[4];
        u16x4 hi4, lo4;
#pragma unroll
        for (int r = 0; r < 4; ++r) {
          float sv = fmaxf(acc[tt][r] * (1.f / 65536.f) + bias_r[r], 0.f);
          fr[r] = sv * alr[r];
          float sc = sv * 256.f;
          _Float16 hh = (_Float16)sc;
          HU a2, b2;
          a2.h = hh;
          b2.h = (_Float16)(sc - (float)hh);
          hi4[r] = a2.u;
          lo4[r] = b2.u;
        }
        size_t base =
            (((size_t)b * 121 + p) * 134 + d16g * 16 + n + 3) * 16 + q * 4;
        *(u16x4*)&pk_hi[base] = hi4;
        *(u16x4*)&pk_lo[base] = lo4;
        u16x4 z = {0, 0, 0, 0};
        if (d16g == 0 && n < 3) {
          size_t hb = (((size_t)b * 121 + p) * 134 + n) * 16 + q * 4;
          *(u16x4*)&pk_hi[hb] = z;
          *(u16x4*)&pk_lo[hb] = z;
        }
        if (d16g == 7 && n >= 13) {
          size_t hb = (((size_t)b * 121 + p) * 134 + n + 118) * 16 + q * 4;
          *(u16x4*)&pk_hi[hb] = z;
          *(u16x4*)&pk_lo[hb] = z;
        }
        // cpr partial over this d16's 16 depths; one writer per slot
#pragma unroll
        for (int r = 0; r < 4; ++r) {
          float v = fr[r];
          v += __shfl_xor(v, 1, 64);
          v += __shfl_xor(v, 2, 64);
          v += __shfl_xor(v, 4, 64);
          v += __shfl_xor(v, 8, 64);
          if (n == 0)
            fpart[(((size_t)d16g * 64 + b) * 16 + q * 4 + r) * 121 + p] = v;
        }
      }
    }
  }
}

// ---------------- conv2/conv3: MFMA f16x2-split, window-reuse K-loop -------
// B-tile LDS layout: [part][row][col][dloc][icq][ic8]  (icq interleaved ->
// each ds_read_b128 wave access is one contiguous window, conflict-free).
// Staging is UNIFORM global_load_lds; padded panels read the zero page.
// cpr partials -> fpart[d16][b][oc][p] (deterministic; each slot written once)
template <bool WRITE_PK>
__global__ __launch_bounds__(512, 2) void conv_mfma_kernel(
    const unsigned short* __restrict__ pin_hi,
    const unsigned short* __restrict__ pin_lo,
    const unsigned short* __restrict__ arep, const float* __restrict__ bias,
    const float* __restrict__ al, const unsigned short* __restrict__ zpage,
    unsigned short* __restrict__ pout_hi, unsigned short* __restrict__ pout_lo,
    float* __restrict__ fpart) {
  __shared__ _Float16 lds[2 * LHALF];
  const int t = threadIdx.x;
  const int bx = blockIdx.x, d16 = blockIdx.y, b = blockIdx.z;
  const int lane = t & 63, wave = t >> 6;
  const int n = lane & 15, q = lane >> 4;
  const int hs = wave >> 2, wg = wave & 3;
  const int h = 2 * bx + hs;  // 0..11 (11 = dummy)

#pragma unroll
  for (int i = 0; i < 9; ++i) {
    int u = t + i * 512;
    int lbo = __builtin_amdgcn_readfirstlane((wave << 6) + i * 512);
    if (u < 4576) {
      int part = (u >= 2288) ? 1 : 0;
      int qq = u - part * 2288;
      int panel = qq / 44;            // 52 panels (4 rows x 13 cols)
      int rem = qq - panel * 44;      // [dloc][icq]
      int dloc = rem >> 1;
      int icq = rem & 1;
      int rr = panel / 13, cc = panel - rr * 13;
      int hh = 2 * bx + rr - 1, ww = cc - 1;
      bool ok = (hh >= 0) & (hh < 11) & (ww >= 0) & (ww < 11);
      const unsigned short* srcp = part ? pin_lo : pin_hi;
      const unsigned short* g =
          ok ? &srcp[(((size_t)b * 121 + hh * 11 + ww) * 134 + d16 * 16 +
                      dloc) *
                         16 +
                     icq * 8]
             : zpage;
      __builtin_amdgcn_global_load_lds((const gu32*)g,
                                       (lu32*)&lds[(size_t)lbo * 8], 16, 0, 0);
    }
  }
  float bias_r[4], alr[4];
#pragma unroll
  for (int r = 0; r < 4; ++r) {
    bias_r[r] = bias[q * 4 + r];
    alr[r] = al[(q * 4 + r) * 128 + d16 * 16 + n];
  }
  __syncthreads();

  const int wl0 = wg * 3;
  int cb[5], cbk[5];
  // [dloc][icq][8]: dloc stride = 16 halves, icq stride = 8 halves
  const int base_qn = (q & 1) * 8 + n * 16 + hs * 4576;
  const int kdh = (lane & 32) ? 16 : 0;
#pragma unroll
  for (int j = 0; j < 5; ++j) {
    int colj = wl0 + j;
    if (colj > 12) colj = 12;
    cb[j] = base_qn + colj * 352;
    cbk[j] = cb[j] + kdh;
  }

  float4v acc[3];
#pragma unroll
  for (int tt = 0; tt < 3; ++tt) acc[tt] = (float4v){0.f, 0.f, 0.f, 0.f};

#pragma unroll
  for (int kh = 0; kh < 3; ++kh) {
#pragma unroll
    for (int kdp = 0; kdp < 4; ++kdp) {
      half8 whi[5], wlo[5];
#pragma unroll
      for (int j = 0; j < 5; ++j) {
        int a = ((kdp < 3) ? cbk[j] : cb[j]) + kh * 4576 + kdp * 32;
        whi[j] = *(const half8*)&lds[a];
        wlo[j] = *(const half8*)&lds[a + LHALF];
      }
#pragma unroll
      for (int kw = 0; kw < 3; ++kw) {
        const int c2 = (kh * 4 + kdp) * 3 + kw;
        half8 ahi = *(const half8*)&arep[((c2 * 2 + 0) * 64 + lane) * 8];
        half8 alo = *(const half8*)&arep[((c2 * 2 + 1) * 64 + lane) * 8];
#pragma unroll
        for (int tt = 0; tt < 3; ++tt) {
          const int jj = tt + kw;
          acc[tt] = __builtin_amdgcn_mfma_f32_16x16x32_f16(ahi, whi[jj],
                                                           acc[tt], 0, 0, 0);
          acc[tt] = __builtin_amdgcn_mfma_f32_16x16x32_f16(ahi, wlo[jj],
                                                           acc[tt], 0, 0, 0);
          acc[tt] = __builtin_amdgcn_mfma_f32_16x16x32_f16(alo, whi[jj],
                                                           acc[tt], 0, 0, 0);
        }
      }
    }
  }

#pragma unroll
  for (int tt = 0; tt < 3; ++tt) {
    const int wl = wg * 3 + tt;
    if (h < 11 && wl < 11) {
      const int p = h * 11 + wl;
      float fr[4];
      u16x4 hi4, lo4;
#pragma unroll
      for (int r = 0; r < 4; ++r) {
        float sv = fmaxf(acc[tt][r] * (1.f / 65536.f) + bias_r[r], 0.f);
        fr[r] = sv * alr[r];
        if (WRITE_PK) {
          float s = sv * 256.f;
          _Float16 hh = (_Float16)s;
          HU a, bb;
          a.h = hh;
          bb.h = (_Float16)(s - (float)hh);
          hi4[r] = a.u;
          lo4[r] = bb.u;
        }
      }
      if (WRITE_PK) {
        size_t base =
            (((size_t)b * 121 + p) * 134 + d16 * 16 + n + 3) * 16 + q * 4;
        *(u16x4*)&pout_hi[base] = hi4;
        *(u16x4*)&pout_lo[base] = lo4;
        u16x4 z = {0, 0, 0, 0};
        if (d16 == 0 && n < 3) {
          size_t hb = (((size_t)b * 121 + p) * 134 + n) * 16 + q * 4;
          *(u16x4*)&pout_hi[hb] = z;
          *(u16x4*)&pout_lo[hb] = z;
        }
        if (d16 == 7 && n >= 13) {
          size_t hb = (((size_t)b * 121 + p) * 134 + n + 118) * 16 + q * 4;
          *(u16x4*)&pout_hi[hb] = z;
          *(u16x4*)&pout_lo[hb] = z;
        }
      }
      // cpr partial: reduce over the 16 d's of this block; one writer per slot
#pragma unroll
      for (int r = 0; r < 4; ++r) {
        float v = fr[r];
        v += __shfl_xor(v, 1, 64);
        v += __shfl_xor(v, 2, 64);
        v += __shfl_xor(v, 4, 64);
        v += __shfl_xor(v, 8, 64);
        if (n == 0)
          fpart[(((size_t)d16 * 64 + b) * 16 + q * 4 + r) * 121 + p] = v;
      }
    }
  }
}

// ---------------- sp path (+sa side-outs, +f4/f5 recompute in LDS) ---------
// grid (64 b, 5 i), 256 thr. F source:
//   i=0: sum_d16 fpart0   i=1: sum_d16 fpart1 (fixed order)
//   i=2: sum fpart2       i=3: conv_l0(sum fpart2)
//   i=4: conv_l1(conv_l0(sum fpart2))
__global__ __launch_bounds__(256) void sp_prep_kernel(
    const float* __restrict__ fpart0, const float* __restrict__ fpart1,
    const float* __restrict__ fpart2, const float* __restrict__ x_t,
    const float* __restrict__ wrep2d, const float* __restrict__ b2d45,
    const float* __restrict__ seg_w, const float* __restrict__ seg_b,
    const float* __restrict__ so_w, const float* __restrict__ so_b,
    const float* __restrict__ sp_wa, const float* __restrict__ sp_ba,
    const float* __restrict__ sp_wb, const float* __restrict__ sp_bb,
    const float* __restrict__ sp_sw, const float* __restrict__ sp_sb,
    float* __restrict__ sa_sd, float* __restrict__ sp_sd) {
  const int b = blockIdx.x, i = blockIdx.y;
  const int t = threadIdx.x;
  __shared__ __align__(16) float fl[16 * 121];
  __shared__ __align__(16) float buf[16 * 121];
  __shared__ __align__(16) float wlds[2304];  // conv2d layer weights
  __shared__ float swlds[144];                // seg conv weights
  __shared__ float act[121];
  __shared__ float diffs[121];
  __shared__ int sel[5];
  __shared__ float s7[7], xc7[7];
  __shared__ float P[2][7][7];
  __shared__ float y1[16][9];
  __shared__ float y2[16];

  // stage seg weights (uniform broadcast reads later)
  for (int j = t; j < 144; j += 256) swlds[j] = seg_w[i * 144 + j];

  // load base feat (fixed d16 order per element -> deterministic; float4)
  {
    float* ldst = (i < 3) ? fl : buf;
    const float* fp0 = (i == 0) ? fpart0 : (i == 1) ? fpart1 : fpart2;
    const size_t boff = (size_t)b * 1936;
    for (int idx4 = t; idx4 < 484; idx4 += 256) {
      float4v s = {0.f, 0.f, 0.f, 0.f};
#pragma unroll
      for (int d16 = 0; d16 < 8; ++d16)
        s += *(const float4v*)&fp0[(size_t)d16 * F_SLICE + boff + idx4 * 4];
      float4v r;
#pragma unroll
      for (int e = 0; e < 4; ++e) r[e] = fmaxf(s[e], 0.f);
      *(float4v*)&ldst[idx4 * 4] = r;
    }
  }
  __syncthreads();

// weights from wlds (staged per layer); 2 threads per position x 8 oc each.
// Per-oc accumulation order (ic,u,v) identical to the 16-oc version ->
// bit-identical outputs.
#define CONV2D_LAYER(SRC, DST, L)                                        \
  if (t < 242) {                                                         \
    int half_ = t / 121;                                                 \
    int pos_ = t - half_ * 121;                                          \
    int h_ = pos_ / 11, w_ = pos_ - h_ * 11;                             \
    int ob_ = half_ * 8;                                                 \
    float a_[8];                                                         \
    _Pragma("unroll") for (int o = 0; o < 8; ++o) a_[o] =                \
        b2d45[(L)*16 + ob_ + o];                                         \
    for (int ic = 0; ic < 16; ++ic) {                                    \
      _Pragma("unroll") for (int u = 0; u < 3; ++u) {                    \
        int hh_ = h_ + u - 1;                                            \
        _Pragma("unroll") for (int v = 0; v < 3; ++v) {                  \
          int ww_ = w_ + v - 1;                                          \
          float val_ = (hh_ >= 0 && hh_ < 11 && ww_ >= 0 && ww_ < 11)    \
                           ? (SRC)[ic * 121 + hh_ * 11 + ww_]            \
                           : 0.f;                                        \
          const float* wp_ = wlds + (ic * 9 + u * 3 + v) * 16 + ob_;     \
          float wr_[8];                                                  \
          _Pragma("unroll") for (int o = 0; o < 8; ++o) wr_[o] = wp_[o]; \
          _Pragma("unroll") for (int o = 0; o < 8; ++o) a_[o] =          \
              fmaf(val_, wr_[o], a_[o]);                                 \
        }                                                                \
      }                                                                  \
    }                                                                    \
    _Pragma("unroll") for (int o = 0; o < 8; ++o)                        \
        (DST)[(ob_ + o) * 121 + pos_] = fmaxf(a_[o], 0.f);               \
  }

  if (i >= 3) {
    // stage layer-0 weights
    for (int j4 = t; j4 < 576; j4 += 256)
      *(float4v*)&wlds[j4 * 4] = *(const float4v*)&wrep2d[j4 * 4];
    __syncthreads();
    CONV2D_LAYER(buf, fl, 0)
    __syncthreads();
    if (i == 4) {
      // stage layer-1 weights (layer-0 reads done at the barrier above)
      for (int j4 = t; j4 < 576; j4 += 256)
        *(float4v*)&wlds[j4 * 4] = *(const float4v*)&wrep2d[2304 + j4 * 4];
      __syncthreads();
      CONV2D_LAYER(fl, buf, 1)
      __syncthreads();
    }
  }
  const float* F = (i == 4) ? buf : fl;

  // sa side-output for (b, i)
  if (t < 16) {
    float s = so_b[i * 16 + t];
    const float* swp = so_w + (i * 16 + t) * 16;
    for (int c = 0; c < 16; ++c) s += F[c * 121 + 60] * swp[c];
    sa_sd[((size_t)i * 64 + b) * 16 + t] = s;
  }

  // seg conv (no relu); weights from LDS broadcast.  EXACT structure kept
  // (feeds the brittle top-k selection).
  if (t < 121) {
    int h = t / 11, w = t - h * 11;
    float a = seg_b[i];
    for (int ic = 0; ic < 16; ++ic) {
      float w9[9];
#pragma unroll
      for (int j = 0; j < 9; ++j) w9[j] = swlds[ic * 9 + j];
#pragma unroll
      for (int u = 0; u < 3; ++u) {
        int hh = h + u - 1;
#pragma unroll
        for (int v = 0; v < 3; ++v) {
          int ww = w + v - 1;
          if (hh >= 0 && hh < 11 && ww >= 0 && ww < 11)
            a = fmaf(F[ic * 121 + hh * 11 + ww], w9[u * 3 + v], a);
        }
      }
    }
    act[t] = a;
  }
  __syncthreads();
  if (t < 121) diffs[t] = fabsf(act[t] - act[60]);
  __syncthreads();

  for (int k = 0; k < 5; ++k) {
    if (t < 64) {
      float d0 = diffs[t];
      int i0 = t;
      float d1 = (t + 64 < 121) ? diffs[t + 64] : 3.0e38f;
      if (d1 < d0) { d0 = d1; i0 = t + 64; }
#pragma unroll
      for (int off = 32; off; off >>= 1) {
        float od = __shfl_down(d0, off, 64);
        int oi = __shfl_down(i0, off, 64);
        if (od < d0 || (od == d0 && oi < i0)) { d0 = od; i0 = oi; }
      }
      if (t == 0) {
        sel[k] = i0;
        diffs[i0] = 3.0e38f;
      }
    }
    __syncthreads();
  }

  if (t < 7) {
    const float* xb = x_t + (size_t)b * 121 * 128;
    float s = 0.f;
    for (int k = 0; k < 5; ++k) s += xb[(size_t)sel[k] * 128 + 61 + t];
    s7[t] = s;
    xc7[t] = xb[60 * 128 + 61 + t];
  }
  __syncthreads();
  if (t < 49) {
    int r = t / 7, c = t - r * 7;
    float d0 = s7[c];
    if (fabsf(d0) < 0.01f) d0 = 0.01f;
    float d1 = xc7[c];
    if (fabsf(d1) < 0.01f) d1 = 0.01f;
    P[0][r][c] = s7[r] / d0;
    P[1][r][c] = xc7[r] / d1;
  }
  __syncthreads();
  for (int item = t; item < 144; item += 256) {
    int ch = item / 9, pos = item - ch * 9;
    int a0 = pos / 3, b0 = pos - a0 * 3;
    float a = sp_ba[i * 16 + ch];
    const float* wa = sp_wa + ((size_t)(i * 16 + ch) * 2) * 9;
#pragma unroll
    for (int icc = 0; icc < 2; ++icc)
#pragma unroll
      for (int u = 0; u < 3; ++u)
#pragma unroll
        for (int v = 0; v < 3; ++v)
          a = fmaf(P[icc][2 * a0 + u][2 * b0 + v], wa[icc * 9 + u * 3 + v], a);
    y1[ch][pos] = fmaxf(a, 0.f);
  }
  __syncthreads();
  if (t < 16) {
    float a = sp_bb[i * 16 + t];
    const float* wb = sp_wb + (size_t)(i * 16 + t) * 16 * 9;
    for (int ch = 0; ch < 16; ++ch)
#pragma unroll
      for (int pos = 0; pos < 9; ++pos)
        a = fmaf(y1[ch][pos], wb[ch * 9 + pos], a);
    y2[t] = fmaxf(a, 0.f);
  }
  __syncthreads();
  if (t < 16) {
    float a = sp_sb[i * 16 + t];
    const float* swp = sp_sw + (size_t)(i * 16 + t) * 16;
    for (int ch = 0; ch < 16; ++ch) a = fmaf(y2[ch], swp[ch], a);
    sp_sd[((size_t)i * 64 + b) * 16 + t] = a;
  }
}

// ---------------- final fuse ------------------------------------------------
__global__ __launch_bounds__(256) void fuse_kernel(
    const float* __restrict__ sa_sd, const float* __restrict__ sp_sd,
    const float* __restrict__ fp, float* __restrict__ out) {
  int g = blockIdx.x * 256 + threadIdx.x;
  if (g >= 1024) return;
  int b = g >> 4, o = g & 15;
  float tot = 0.f;
  for (int i = 0; i < 5; ++i) {
    tot += fp[i] * sa_sd[((size_t)i * 64 + b) * 16 + o];
    tot += fp[5 + i] * sp_sd[((size_t)i * 64 + b) * 16 + o];
  }
  out[g] = tot;
}

extern "C" void kernel_launch(void* const* d_in, const int* in_sizes, int n_in,
                              void* d_out, int out_size, void* d_ws,
                              size_t ws_size, hipStream_t stream) {
  const float* x = (const float*)d_in[0];
  const float* w3d1 = (const float*)d_in[1];
  const float* b3d1 = (const float*)d_in[2];
  const float* w3d23 = (const float*)d_in[3];
  const float* b3d23 = (const float*)d_in[4];
  const float* cpr_w = (const float*)d_in[5];
  const float* w2d45 = (const float*)d_in[6];
  const float* b2d45 = (const float*)d_in[7];
  const float* seg_w = (const float*)d_in[8];
  const float* seg_b = (const float*)d_in[9];
  const float* so_w = (const float*)d_in[10];
  const float* so_b = (const float*)d_in[11];
  const float* sp_wa = (const float*)d_in[12];
  const float* sp_ba = (const float*)d_in[13];
  const float* sp_wb = (const float*)d_in[14];
  const float* sp_bb = (const float*)d_in[15];
  const float* sp_sw = (const float*)d_in[16];
  const float* sp_sb = (const float*)d_in[17];
  const float* fpar = (const float*)d_in[18];

  float* ws = (float*)d_ws;
  float* x_t = ws;                        // 991232 f
  float* a_sm = x_t + 991232;             // 6144 f
  float* fpart0 = a_sm + 6144;            // 8*F_SLICE f
  float* fpart1 = fpart0 + 8 * F_SLICE;   // 8*F_SLICE f
  float* fpart2 = fpart1 + 8 * F_SLICE;   // 8*F_SLICE f
  float* sp_sd = fpart2 + 8 * F_SLICE;    // 5120 f
  float* sa_sd = sp_sd + 5120;            // 5120 f
  float* wrep2d = sa_sd + 5120;           // 4608 f
  unsigned short* pk1h = (unsigned short*)(wrep2d + 4608);
  unsigned short* pk1l = pk1h + PKE;
  unsigned short* pk2h = pk1l + PKE;
  unsigned short* pk2l = pk2h + PKE;
  unsigned short* arep = pk2l + PKE;      // 2*AREP_CV u16
  unsigned short* arep1 = arep + 2 * AREP_CV;  // 3072 u16
  unsigned short* zpage = arep1 + 3072;   // 1024 u16 (zeroed every launch)
  // xpad planes overlay fpart1/fpart2 (prep writes, conv1_mfma reads;
  // fpart1/fpart2 are written only afterwards by conv_mfma #1/#2)
  unsigned short* xpadh = (unsigned short*)fpart1;  // XPADE u16
  unsigned short* xpadl = xpadh + XPADE;            // XPADE u16

  prep_kernel<<<431, 256, 0, stream>>>(x, cpr_w, w3d1, w2d45, w3d23, x_t,
                                       a_sm, wrep2d, arep, arep1, xpadh,
                                       xpadl, zpage);

  conv1_mfma_kernel<<<dim3(6, 4, 64), 512, 0, stream>>>(
      xpadh, xpadl, arep1, b3d1, a_sm, pk1h, pk1l, fpart0);
  conv_mfma_kernel<true><<<dim3(6, 8, 64), 512, 0, stream>>>(
      pk1h, pk1l, arep, b3d23, a_sm + 2048, zpage, pk2h, pk2l, fpart1);
  conv_mfma_kernel<false><<<dim3(6, 8, 64), 512, 0, stream>>>(
      pk2h, pk2l, arep + AREP_CV, b3d23 + 16, a_sm + 4096, zpage, nullptr,
      nullptr, fpart2);

  sp_prep_kernel<<<dim3(64, 5), 256, 0, stream>>>(
      fpart0, fpart1, fpart2, x_t, wrep2d, b2d45, seg_w, seg_b, so_w, so_b,
      sp_wa, sp_ba, sp_wb, sp_bb, sp_sw, sp_sb, sa_sd, sp_sd);
  fuse_kernel<<<4, 256, 0, stream>>>(sa_sd, sp_sd, fpar, (float*)d_out);
}

// Round 11
// 366.241 us; speedup vs baseline: 1.1225x; 1.0242x over previous
//
#include <hip/hip_runtime.h>
#include <hip/hip_bf16.h>

// ---------------------------------------------------------------------------
// Segment_3DCenter round 22:
//  - prep: b-section split to 2 blocks/batch (p-halves) -> 128 blocks, each
//    loading only its half of x; xpad emission vectorized u16x8 (was scalar
//    u16 stores).  Bit-identical values; halves prep's critical path.
//    Branch boundaries shifted +64 (grid 495).
//  - conv_mfma: R14-exact (closed lane).  conv1_mfma / sp_prep (R21 oc-split)
//    / fuse unchanged from round 21 (best verified, 375.1us).
// ---------------------------------------------------------------------------

#define F_SLICE (64 * 16 * 121)          // 123904
#define PKE (64 * 121 * 134 * 16)        // u16 elements per pk plane
#define LHALF 18304                      // LDS halves per part (52*352)
#define AREP_CV 36864                    // u16 per conv in arep (36*2*64*8)
#define XPADE (64 * 121 * 136)           // u16 per xpad plane (1,053,184)

typedef _Float16 half8 __attribute__((ext_vector_type(8)));
typedef float float4v __attribute__((ext_vector_type(4)));
typedef unsigned short u16x8 __attribute__((ext_vector_type(8)));
typedef unsigned short u16x4 __attribute__((ext_vector_type(4)));

typedef __attribute__((address_space(1))) unsigned int gu32;
typedef __attribute__((address_space(3))) unsigned int lu32;

union HU { _Float16 h; unsigned short u; };

// ---------------- prep: transpose + xpad + softmax + repacks + arep --------
__global__ __launch_bounds__(256) void prep_kernel(
    const float* __restrict__ x, const float* __restrict__ cpr_w,
    const float* __restrict__ w3d1, const float* __restrict__ w2d45,
    const float* __restrict__ w3d23, float* __restrict__ x_t,
    float* __restrict__ a_sm, float* __restrict__ wrep2d,
    unsigned short* __restrict__ arep, unsigned short* __restrict__ arep1,
    unsigned short* __restrict__ xpadh, unsigned short* __restrict__ xpadl,
    unsigned short* __restrict__ zpage) {
  const int bx = blockIdx.x, t = threadIdx.x;
  if (bx < 128) {
    // 2 blocks per batch: p-halves [0,61) and [61,121)
    __shared__ float tile[128][63];
    const int b = bx >> 1;
    const int half = bx & 1;
    const int p0 = half ? 61 : 0;
    const int cnt = half ? 60 : 61;
    const float* xb = x + (size_t)b * 128 * 121;
    for (int idx = t; idx < 128 * cnt; idx += 256) {
      int c = idx / cnt, pp = idx - c * cnt;
      tile[c][pp] = xb[c * 121 + p0 + pp];
    }
    __syncthreads();
    float* ob = x_t + (size_t)b * 121 * 128;
    for (int idx = t; idx < cnt * 128; idx += 256) {
      int pp = idx >> 7, c = idx & 127;
      ob[(p0 + pp) * 128 + c] = tile[c][pp];
    }
    // f16 hi/lo zero-padded planes [121][136], value = x*256 (u16x8 stores)
    unsigned short* xh = xpadh + (size_t)b * 16456;
    unsigned short* xl = xpadl + (size_t)b * 16456;
    for (int g = t; g < 17 * cnt; g += 256) {
      int pp = g / 17, gg = g - pp * 17;
      int d0 = gg * 8;
      int p = p0 + pp;
      u16x8 hv, lv;
#pragma unroll
      for (int e = 0; e < 8; ++e) {
        int d = d0 + e;
        float v = 0.f;
        if (d >= 3 && d < 131) v = tile[d - 3][pp] * 256.f;
        _Float16 hi = (_Float16)v;
        HU a2, b2;
        a2.h = hi;
        b2.h = (_Float16)(v - (float)hi);
        hv[e] = a2.u;
        lv[e] = b2.u;
      }
      *(u16x8*)&xh[p * 136 + d0] = hv;
      *(u16x8*)&xl[p * 136 + d0] = lv;
    }
  } else if (bx < 176) {
    __shared__ float red[128];
    const int row = bx - 128;
    float v = (t < 128) ? cpr_w[row * 128 + t] : -3.0e38f;
    if (t < 128) red[t] = v;
    __syncthreads();
    for (int s = 64; s; s >>= 1) {
      if (t < s) red[t] = fmaxf(red[t], red[t + s]);
      __syncthreads();
    }
    float m = red[0];
    __syncthreads();
    float e = (t < 128) ? expf(v - m) : 0.f;
    if (t < 128) red[t] = e;
    __syncthreads();
    for (int s = 64; s; s >>= 1) {
      if (t < s) red[t] += red[t + s];
      __syncthreads();
    }
    if (t < 128) a_sm[row * 128 + t] = e / red[0];
  } else if (bx < 206) {
    int r = (bx - 176) * 256 + t;
    if (r < 3072) {
      // arep1[kh][part][lane][8]: k = 8q+j -> (kw=q (3+pad), kd=j (7+pad))
      int j = r & 7;
      int lane = (r >> 3) & 63;
      int part = (r >> 9) & 1;
      int kh = r >> 10;
      int m = lane & 15, q = lane >> 4;
      float w = 0.f;
      if (q < 3 && j < 7) w = w3d1[m * 63 + j * 9 + kh * 3 + q] * 256.f;
      _Float16 hi = (_Float16)w;
      HU o;
      o.h = part ? (_Float16)(w - (float)hi) : hi;
      arep1[r] = o.u;
    } else if (r < 3072 + 4608) {
      int r2 = r - 3072;
      int o = r2 & 15;
      int uv = (r2 >> 4) % 9;
      int ic = (r2 / 144) % 16;
      int layer = r2 / 2304;
      wrep2d[r2] = w2d45[((layer * 16 + o) * 16 + ic) * 9 + uv];
    }
  } else if (bx < 494) {
    int idx = (bx - 206) * 256 + t;
    if (idx < 2 * AREP_CV) {
      int j = idx & 7;
      int lane = (idx >> 3) & 63;
      int part = (idx >> 9) & 1;
      int rem = idx >> 10;
      int chunk = rem % 36;
      int cv = rem / 36;
      int kw = chunk % 3;
      int grp = chunk / 3;
      int kdp = grp & 3;
      int kh = grp >> 2;
      int m = lane & 15, q = lane >> 4;
      int kd = 2 * kdp + (q >> 1);
      int ic = (q & 1) * 8 + j;
      float w = 0.f;
      if (kd < 7)
        w = w3d23[((cv * 16 + m) * 16 + ic) * 63 + kd * 9 + kh * 3 + kw] *
            256.f;
      _Float16 hi = (_Float16)w;
      HU out;
      out.h = (part == 0) ? hi : (_Float16)(w - (float)hi);
      arep[idx] = out.u;
    }
  } else {
    // zero page for padded-panel staging loads (rewritten every launch)
    if (t < 128) {
      u16x8 z = {0, 0, 0, 0, 0, 0, 0, 0};
      *(u16x8*)&zpage[t * 8] = z;
    }
  }
}

// ---------------- conv1 via MFMA: xpad hi/lo -> pk1 planes + fpart0 --------
// grid (6 h-pairs, 4 depth-32-groups, 64 b), 512 thr = 8 waves (2 hs x 4 wg).
// K=32 per MFMA = 4 kw-slots(3 real) x 8 kd-taps(7 real); one pass per kh.
__global__ __launch_bounds__(512, 2) void conv1_mfma_kernel(
    const unsigned short* __restrict__ xph,
    const unsigned short* __restrict__ xpl,
    const unsigned short* __restrict__ arep1, const float* __restrict__ bias,
    const float* __restrict__ al, unsigned short* __restrict__ pk_hi,
    unsigned short* __restrict__ pk_lo, float* __restrict__ fpart) {
  // LDS: 104 windows (2 part x 4 row x 13 col) x 32 granules x 8 halfs
  __shared__ _Float16 lds1[104 * 256];
  const int t = threadIdx.x;
  const int bx = blockIdx.x, gy = blockIdx.y, b = blockIdx.z;
  const int lane = t & 63, wave = t >> 6;
  const int n = lane & 15, q = lane >> 4;
  const int hs = wave >> 2, wg = wave & 3;
  const int h = 2 * bx + hs;  // 0..11 (11 = dummy)
  const int D0 = gy * 32;

  // ---- staging: im2col windows, value[dloc][kd] = xpad[D0 + dloc + kd] ----
  {
    const int g = t & 31;  // dest granule (= dloc)
    const int s = g & 7;   // per-thread constant shift (halfs)
    const int w0 = t >> 5;
#pragma unroll
    for (int k = 0; k < 7; ++k) {
      int wid = w0 + k * 16;
      if (wid < 104) {
        int part = wid >= 52;
        int w2 = wid - part * 52;
        int rr = w2 / 13;
        int cc = w2 - rr * 13;
        int hh = 2 * bx - 1 + rr, ww = cc - 1;
        u16x8 v0 = {0, 0, 0, 0, 0, 0, 0, 0};
        u16x8 v1 = {0, 0, 0, 0, 0, 0, 0, 0};
        if (hh >= 0 && hh < 11 && ww >= 0 && ww < 11) {
          const unsigned short* src = (part ? xpl : xph) +
                                      ((size_t)b * 121 + hh * 11 + ww) * 136 +
                                      D0 + (g & ~7);
          v0 = *(const u16x8*)src;
          v1 = *(const u16x8*)(src + 8);
        }
        u16x8 ov;
#define SHIFT_CASE(S)                                                   \
  case S: {                                                             \
    _Pragma("unroll") for (int e = 0; e < 8; ++e) ov[e] =               \
        (((S) + e) < 8) ? v0[((S) + e) & 7] : v1[((S) + e) & 7];        \
  } break;
        switch (s) {
          SHIFT_CASE(0)
          SHIFT_CASE(1)
          SHIFT_CASE(2)
          SHIFT_CASE(3)
          SHIFT_CASE(4)
          SHIFT_CASE(5)
          SHIFT_CASE(6)
          SHIFT_CASE(7)
        }
#undef SHIFT_CASE
        *(u16x8*)&lds1[wid * 256 + g * 8] = ov;
      }
    }
  }

  // A-frags (weights) + per-lane constants
  half8 ahi[3], alo[3];
#pragma unroll
  for (int kh = 0; kh < 3; ++kh) {
    ahi[kh] = *(const half8*)&arep1[(kh * 2 + 0) * 512 + lane * 8];
    alo[kh] = *(const half8*)&arep1[(kh * 2 + 1) * 512 + lane * 8];
  }
  int colq[3];
#pragma unroll
  for (int tt = 0; tt < 3; ++tt) {
    int c = wg * 3 + tt + q;  // = (w-1+kw)+1 ; kw = q
    colq[tt] = (c > 12) ? 12 : c;  // clamp only hits zero-weight/dummy lanes
  }
  float bias_r[4];
#pragma unroll
  for (int r = 0; r < 4; ++r) bias_r[r] = bias[q * 4 + r];
  __syncthreads();

#pragma unroll
  for (int d16loc = 0; d16loc < 2; ++d16loc) {
    const int d16g = gy * 2 + d16loc;
    const int dbase = d16loc * 16 + n;  // dloc
    float4v acc[3];
#pragma unroll
    for (int tt = 0; tt < 3; ++tt) acc[tt] = (float4v){0.f, 0.f, 0.f, 0.f};
#pragma unroll
    for (int kh = 0; kh < 3; ++kh) {
      const int rowoff = (hs + kh) * 13;
#pragma unroll
      for (int tt = 0; tt < 3; ++tt) {
        const int wid = rowoff + colq[tt];
        half8 bh = *(const half8*)&lds1[wid * 256 + dbase * 8];
        half8 bl = *(const half8*)&lds1[(wid + 52) * 256 + dbase * 8];
        acc[tt] =
            __builtin_amdgcn_mfma_f32_16x16x32_f16(ahi[kh], bh, acc[tt], 0, 0, 0);
        acc[tt] =
            __builtin_amdgcn_mfma_f32_16x16x32_f16(ahi[kh], bl, acc[tt], 0, 0, 0);
        acc[tt] =
            __builtin_amdgcn_mfma_f32_16x16x32_f16(alo[kh], bh, acc[tt], 0, 0, 0);
      }
    }
    float alr[4];
#pragma unroll
    for (int r = 0; r < 4; ++r)
      alr[r] = al[(q * 4 + r) * 128 + d16g * 16 + n];
#pragma unroll
    for (int tt = 0; tt < 3; ++tt) {
      const int wl = wg * 3 + tt;
      if (h < 11 && wl < 11) {
        const int p = h * 11 + wl;
        float fr[4];
        u16x4 hi4, lo4;
#pragma unroll
        for (int r = 0; r < 4; ++r) {
          float sv = fmaxf(acc[tt][r] * (1.f / 65536.f) + bias_r[r], 0.f);
          fr[r] = sv * alr[r];
          float sc = sv * 256.f;
          _Float16 hh = (_Float16)sc;
          HU a2, b2;
          a2.h = hh;
          b2.h = (_Float16)(sc - (float)hh);
          hi4[r] = a2.u;
          lo4[r] = b2.u;
        }
        size_t base =
            (((size_t)b * 121 + p) * 134 + d16g * 16 + n + 3) * 16 + q * 4;
        *(u16x4*)&pk_hi[base] = hi4;
        *(u16x4*)&pk_lo[base] = lo4;
        u16x4 z = {0, 0, 0, 0};
        if (d16g == 0 && n < 3) {
          size_t hb = (((size_t)b * 121 + p) * 134 + n) * 16 + q * 4;
          *(u16x4*)&pk_hi[hb] = z;
          *(u16x4*)&pk_lo[hb] = z;
        }
        if (d16g == 7 && n >= 13) {
          size_t hb = (((size_t)b * 121 + p) * 134 + n + 118) * 16 + q * 4;
          *(u16x4*)&pk_hi[hb] = z;
          *(u16x4*)&pk_lo[hb] = z;
        }
        // cpr partial over this d16's 16 depths; one writer per slot
#pragma unroll
        for (int r = 0; r < 4; ++r) {
          float v = fr[r];
          v += __shfl_xor(v, 1, 64);
          v += __shfl_xor(v, 2, 64);
          v += __shfl_xor(v, 4, 64);
          v += __shfl_xor(v, 8, 64);
          if (n == 0)
            fpart[(((size_t)d16g * 64 + b) * 16 + q * 4 + r) * 121 + p] = v;
        }
      }
    }
  }
}

// ---------------- conv2/conv3: MFMA f16x2-split, window-reuse K-loop -------
// B-tile LDS layout: [part][row][col][dloc][icq][ic8]  (icq interleaved ->
// each ds_read_b128 wave access is one contiguous window, conflict-free).
// Staging is UNIFORM global_load_lds; padded panels read the zero page.
// cpr partials -> fpart[d16][b][oc][p] (deterministic; each slot written once)
template <bool WRITE_PK>
__global__ __launch_bounds__(512, 2) void conv_mfma_kernel(
    const unsigned short* __restrict__ pin_hi,
    const unsigned short* __restrict__ pin_lo,
    const unsigned short* __restrict__ arep, const float* __restrict__ bias,
    const float* __restrict__ al, const unsigned short* __restrict__ zpage,
    unsigned short* __restrict__ pout_hi, unsigned short* __restrict__ pout_lo,
    float* __restrict__ fpart) {
  __shared__ _Float16 lds[2 * LHALF];
  const int t = threadIdx.x;
  const int bx = blockIdx.x, d16 = blockIdx.y, b = blockIdx.z;
  const int lane = t & 63, wave = t >> 6;
  const int n = lane & 15, q = lane >> 4;
  const int hs = wave >> 2, wg = wave & 3;
  const int h = 2 * bx + hs;  // 0..11 (11 = dummy)

#pragma unroll
  for (int i = 0; i < 9; ++i) {
    int u = t + i * 512;
    int lbo = __builtin_amdgcn_readfirstlane((wave << 6) + i * 512);
    if (u < 4576) {
      int part = (u >= 2288) ? 1 : 0;
      int qq = u - part * 2288;
      int panel = qq / 44;            // 52 panels (4 rows x 13 cols)
      int rem = qq - panel * 44;      // [dloc][icq]
      int dloc = rem >> 1;
      int icq = rem & 1;
      int rr = panel / 13, cc = panel - rr * 13;
      int hh = 2 * bx + rr - 1, ww = cc - 1;
      bool ok = (hh >= 0) & (hh < 11) & (ww >= 0) & (ww < 11);
      const unsigned short* srcp = part ? pin_lo : pin_hi;
      const unsigned short* g =
          ok ? &srcp[(((size_t)b * 121 + hh * 11 + ww) * 134 + d16 * 16 +
                      dloc) *
                         16 +
                     icq * 8]
             : zpage;
      __builtin_amdgcn_global_load_lds((const gu32*)g,
                                       (lu32*)&lds[(size_t)lbo * 8], 16, 0, 0);
    }
  }
  float bias_r[4], alr[4];
#pragma unroll
  for (int r = 0; r < 4; ++r) {
    bias_r[r] = bias[q * 4 + r];
    alr[r] = al[(q * 4 + r) * 128 + d16 * 16 + n];
  }
  __syncthreads();

  const int wl0 = wg * 3;
  int cb[5], cbk[5];
  // [dloc][icq][8]: dloc stride = 16 halves, icq stride = 8 halves
  const int base_qn = (q & 1) * 8 + n * 16 + hs * 4576;
  const int kdh = (lane & 32) ? 16 : 0;
#pragma unroll
  for (int j = 0; j < 5; ++j) {
    int colj = wl0 + j;
    if (colj > 12) colj = 12;
    cb[j] = base_qn + colj * 352;
    cbk[j] = cb[j] + kdh;
  }

  float4v acc[3];
#pragma unroll
  for (int tt = 0; tt < 3; ++tt) acc[tt] = (float4v){0.f, 0.f, 0.f, 0.f};

#pragma unroll
  for (int kh = 0; kh < 3; ++kh) {
#pragma unroll
    for (int kdp = 0; kdp < 4; ++kdp) {
      half8 whi[5], wlo[5];
#pragma unroll
      for (int j = 0; j < 5; ++j) {
        int a = ((kdp < 3) ? cbk[j] : cb[j]) + kh * 4576 + kdp * 32;
        whi[j] = *(const half8*)&lds[a];
        wlo[j] = *(const half8*)&lds[a + LHALF];
      }
#pragma unroll
      for (int kw = 0; kw < 3; ++kw) {
        const int c2 = (kh * 4 + kdp) * 3 + kw;
        half8 ahi = *(const half8*)&arep[((c2 * 2 + 0) * 64 + lane) * 8];
        half8 alo = *(const half8*)&arep[((c2 * 2 + 1) * 64 + lane) * 8];
#pragma unroll
        for (int tt = 0; tt < 3; ++tt) {
          const int jj = tt + kw;
          acc[tt] = __builtin_amdgcn_mfma_f32_16x16x32_f16(ahi, whi[jj],
                                                           acc[tt], 0, 0, 0);
          acc[tt] = __builtin_amdgcn_mfma_f32_16x16x32_f16(ahi, wlo[jj],
                                                           acc[tt], 0, 0, 0);
          acc[tt] = __builtin_amdgcn_mfma_f32_16x16x32_f16(alo, whi[jj],
                                                           acc[tt], 0, 0, 0);
        }
      }
    }
  }

#pragma unroll
  for (int tt = 0; tt < 3; ++tt) {
    const int wl = wg * 3 + tt;
    if (h < 11 && wl < 11) {
      const int p = h * 11 + wl;
      float fr[4];
      u16x4 hi4, lo4;
#pragma unroll
      for (int r = 0; r < 4; ++r) {
        float sv = fmaxf(acc[tt][r] * (1.f / 65536.f) + bias_r[r], 0.f);
        fr[r] = sv * alr[r];
        if (WRITE_PK) {
          float s = sv * 256.f;
          _Float16 hh = (_Float16)s;
          HU a, bb;
          a.h = hh;
          bb.h = (_Float16)(s - (float)hh);
          hi4[r] = a.u;
          lo4[r] = bb.u;
        }
      }
      if (WRITE_PK) {
        size_t base =
            (((size_t)b * 121 + p) * 134 + d16 * 16 + n + 3) * 16 + q * 4;
        *(u16x4*)&pout_hi[base] = hi4;
        *(u16x4*)&pout_lo[base] = lo4;
        u16x4 z = {0, 0, 0, 0};
        if (d16 == 0 && n < 3) {
          size_t hb = (((size_t)b * 121 + p) * 134 + n) * 16 + q * 4;
          *(u16x4*)&pout_hi[hb] = z;
          *(u16x4*)&pout_lo[hb] = z;
        }
        if (d16 == 7 && n >= 13) {
          size_t hb = (((size_t)b * 121 + p) * 134 + n + 118) * 16 + q * 4;
          *(u16x4*)&pout_hi[hb] = z;
          *(u16x4*)&pout_lo[hb] = z;
        }
      }
      // cpr partial: reduce over the 16 d's of this block; one writer per slot
#pragma unroll
      for (int r = 0; r < 4; ++r) {
        float v = fr[r];
        v += __shfl_xor(v, 1, 64);
        v += __shfl_xor(v, 2, 64);
        v += __shfl_xor(v, 4, 64);
        v += __shfl_xor(v, 8, 64);
        if (n == 0)
          fpart[(((size_t)d16 * 64 + b) * 16 + q * 4 + r) * 121 + p] = v;
      }
    }
  }
}

// ---------------- sp path (+sa side-outs, +f4/f5 recompute in LDS) ---------
// grid (64 b, 5 i), 256 thr. F source:
//   i=0: sum_d16 fpart0   i=1: sum_d16 fpart1 (fixed order)
//   i=2: sum fpart2       i=3: conv_l0(sum fpart2)
//   i=4: conv_l1(conv_l0(sum fpart2))
__global__ __launch_bounds__(256) void sp_prep_kernel(
    const float* __restrict__ fpart0, const float* __restrict__ fpart1,
    const float* __restrict__ fpart2, const float* __restrict__ x_t,
    const float* __restrict__ wrep2d, const float* __restrict__ b2d45,
    const float* __restrict__ seg_w, const float* __restrict__ seg_b,
    const float* __restrict__ so_w, const float* __restrict__ so_b,
    const float* __restrict__ sp_wa, const float* __restrict__ sp_ba,
    const float* __restrict__ sp_wb, const float* __restrict__ sp_bb,
    const float* __restrict__ sp_sw, const float* __restrict__ sp_sb,
    float* __restrict__ sa_sd, float* __restrict__ sp_sd) {
  const int b = blockIdx.x, i = blockIdx.y;
  const int t = threadIdx.x;
  __shared__ __align__(16) float fl[16 * 121];
  __shared__ __align__(16) float buf[16 * 121];
  __shared__ __align__(16) float wlds[2304];  // conv2d layer weights
  __shared__ float swlds[144];                // seg conv weights
  __shared__ float act[121];
  __shared__ float diffs[121];
  __shared__ int sel[5];
  __shared__ float s7[7], xc7[7];
  __shared__ float P[2][7][7];
  __shared__ float y1[16][9];
  __shared__ float y2[16];

  // stage seg weights (uniform broadcast reads later)
  for (int j = t; j < 144; j += 256) swlds[j] = seg_w[i * 144 + j];

  // load base feat (fixed d16 order per element -> deterministic; float4)
  {
    float* ldst = (i < 3) ? fl : buf;
    const float* fp0 = (i == 0) ? fpart0 : (i == 1) ? fpart1 : fpart2;
    const size_t boff = (size_t)b * 1936;
    for (int idx4 = t; idx4 < 484; idx4 += 256) {
      float4v s = {0.f, 0.f, 0.f, 0.f};
#pragma unroll
      for (int d16 = 0; d16 < 8; ++d16)
        s += *(const float4v*)&fp0[(size_t)d16 * F_SLICE + boff + idx4 * 4];
      float4v r;
#pragma unroll
      for (int e = 0; e < 4; ++e) r[e] = fmaxf(s[e], 0.f);
      *(float4v*)&ldst[idx4 * 4] = r;
    }
  }
  __syncthreads();

// weights from wlds (staged per layer); 2 threads per position x 8 oc each.
// Per-oc accumulation order (ic,u,v) identical to the 16-oc version ->
// bit-identical outputs.
#define CONV2D_LAYER(SRC, DST, L)                                        \
  if (t < 242) {                                                         \
    int half_ = t / 121;                                                 \
    int pos_ = t - half_ * 121;                                          \
    int h_ = pos_ / 11, w_ = pos_ - h_ * 11;                             \
    int ob_ = half_ * 8;                                                 \
    float a_[8];                                                         \
    _Pragma("unroll") for (int o = 0; o < 8; ++o) a_[o] =                \
        b2d45[(L)*16 + ob_ + o];                                         \
    for (int ic = 0; ic < 16; ++ic) {                                    \
      _Pragma("unroll") for (int u = 0; u < 3; ++u) {                    \
        int hh_ = h_ + u - 1;                                            \
        _Pragma("unroll") for (int v = 0; v < 3; ++v) {                  \
          int ww_ = w_ + v - 1;                                          \
          float val_ = (hh_ >= 0 && hh_ < 11 && ww_ >= 0 && ww_ < 11)    \
                           ? (SRC)[ic * 121 + hh_ * 11 + ww_]            \
                           : 0.f;                                        \
          const float* wp_ = wlds + (ic * 9 + u * 3 + v) * 16 + ob_;     \
          float wr_[8];                                                  \
          _Pragma("unroll") for (int o = 0; o < 8; ++o) wr_[o] = wp_[o]; \
          _Pragma("unroll") for (int o = 0; o < 8; ++o) a_[o] =          \
              fmaf(val_, wr_[o], a_[o]);                                 \
        }                                                                \
      }                                                                  \
    }                                                                    \
    _Pragma("unroll") for (int o = 0; o < 8; ++o)                        \
        (DST)[(ob_ + o) * 121 + pos_] = fmaxf(a_[o], 0.f);               \
  }

  if (i >= 3) {
    // stage layer-0 weights
    for (int j4 = t; j4 < 576; j4 += 256)
      *(float4v*)&wlds[j4 * 4] = *(const float4v*)&wrep2d[j4 * 4];
    __syncthreads();
    CONV2D_LAYER(buf, fl, 0)
    __syncthreads();
    if (i == 4) {
      // stage layer-1 weights (layer-0 reads done at the barrier above)
      for (int j4 = t; j4 < 576; j4 += 256)
        *(float4v*)&wlds[j4 * 4] = *(const float4v*)&wrep2d[2304 + j4 * 4];
      __syncthreads();
      CONV2D_LAYER(fl, buf, 1)
      __syncthreads();
    }
  }
  const float* F = (i == 4) ? buf : fl;

  // sa side-output for (b, i)
  if (t < 16) {
    float s = so_b[i * 16 + t];
    const float* swp = so_w + (i * 16 + t) * 16;
    for (int c = 0; c < 16; ++c) s += F[c * 121 + 60] * swp[c];
    sa_sd[((size_t)i * 64 + b) * 16 + t] = s;
  }

  // seg conv (no relu); weights from LDS broadcast.  EXACT structure kept
  // (feeds the brittle top-k selection).
  if (t < 121) {
    int h = t / 11, w = t - h * 11;
    float a = seg_b[i];
    for (int ic = 0; ic < 16; ++ic) {
      float w9[9];
#pragma unroll
      for (int j = 0; j < 9; ++j) w9[j] = swlds[ic * 9 + j];
#pragma unroll
      for (int u = 0; u < 3; ++u) {
        int hh = h + u - 1;
#pragma unroll
        for (int v = 0; v < 3; ++v) {
          int ww = w + v - 1;
          if (hh >= 0 && hh < 11 && ww >= 0 && ww < 11)
            a = fmaf(F[ic * 121 + hh * 11 + ww], w9[u * 3 + v], a);
        }
      }
    }
    act[t] = a;
  }
  __syncthreads();
  if (t < 121) diffs[t] = fabsf(act[t] - act[60]);
  __syncthreads();

  for (int k = 0; k < 5; ++k) {
    if (t < 64) {
      float d0 = diffs[t];
      int i0 = t;
      float d1 = (t + 64 < 121) ? diffs[t + 64] : 3.0e38f;
      if (d1 < d0) { d0 = d1; i0 = t + 64; }
#pragma unroll
      for (int off = 32; off; off >>= 1) {
        float od = __shfl_down(d0, off, 64);
        int oi = __shfl_down(i0, off, 64);
        if (od < d0 || (od == d0 && oi < i0)) { d0 = od; i0 = oi; }
      }
      if (t == 0) {
        sel[k] = i0;
        diffs[i0] = 3.0e38f;
      }
    }
    __syncthreads();
  }

  if (t < 7) {
    const float* xb = x_t + (size_t)b * 121 * 128;
    float s = 0.f;
    for (int k = 0; k < 5; ++k) s += xb[(size_t)sel[k] * 128 + 61 + t];
    s7[t] = s;
    xc7[t] = xb[60 * 128 + 61 + t];
  }
  __syncthreads();
  if (t < 49) {
    int r = t / 7, c = t - r * 7;
    float d0 = s7[c];
    if (fabsf(d0) < 0.01f) d0 = 0.01f;
    float d1 = xc7[c];
    if (fabsf(d1) < 0.01f) d1 = 0.01f;
    P[0][r][c] = s7[r] / d0;
    P[1][r][c] = xc7[r] / d1;
  }
  __syncthreads();
  for (int item = t; item < 144; item += 256) {
    int ch = item / 9, pos = item - ch * 9;
    int a0 = pos / 3, b0 = pos - a0 * 3;
    float a = sp_ba[i * 16 + ch];
    const float* wa = sp_wa + ((size_t)(i * 16 + ch) * 2) * 9;
#pragma unroll
    for (int icc = 0; icc < 2; ++icc)
#pragma unroll
      for (int u = 0; u < 3; ++u)
#pragma unroll
        for (int v = 0; v < 3; ++v)
          a = fmaf(P[icc][2 * a0 + u][2 * b0 + v], wa[icc * 9 + u * 3 + v], a);
    y1[ch][pos] = fmaxf(a, 0.f);
  }
  __syncthreads();
  if (t < 16) {
    float a = sp_bb[i * 16 + t];
    const float* wb = sp_wb + (size_t)(i * 16 + t) * 16 * 9;
    for (int ch = 0; ch < 16; ++ch)
#pragma unroll
      for (int pos = 0; pos < 9; ++pos)
        a = fmaf(y1[ch][pos], wb[ch * 9 + pos], a);
    y2[t] = fmaxf(a, 0.f);
  }
  __syncthreads();
  if (t < 16) {
    float a = sp_sb[i * 16 + t];
    const float* swp = sp_sw + (size_t)(i * 16 + t) * 16;
    for (int ch = 0; ch < 16; ++ch) a = fmaf(y2[ch], swp[ch], a);
    sp_sd[((size_t)i * 64 + b) * 16 + t] = a;
  }
}

// ---------------- final fuse ------------------------------------------------
__global__ __launch_bounds__(256) void fuse_kernel(
    const float* __restrict__ sa_sd, const float* __restrict__ sp_sd,
    const float* __restrict__ fp, float* __restrict__ out) {
  int g = blockIdx.x * 256 + threadIdx.x;
  if (g >= 1024) return;
  int b = g >> 4, o = g & 15;
  float tot = 0.f;
  for (int i = 0; i < 5; ++i) {
    tot += fp[i] * sa_sd[((size_t)i * 64 + b) * 16 + o];
    tot += fp[5 + i] * sp_sd[((size_t)i * 64 + b) * 16 + o];
  }
  out[g] = tot;
}

extern "C" void kernel_launch(void* const* d_in, const int* in_sizes, int n_in,
                              void* d_out, int out_size, void* d_ws,
                              size_t ws_size, hipStream_t stream) {
  const float* x = (const float*)d_in[0];
  const float* w3d1 = (const float*)d_in[1];
  const float* b3d1 = (const float*)d_in[2];
  const float* w3d23 = (const float*)d_in[3];
  const float* b3d23 = (const float*)d_in[4];
  const float* cpr_w = (const float*)d_in[5];
  const float* w2d45 = (const float*)d_in[6];
  const float* b2d45 = (const float*)d_in[7];
  const float* seg_w = (const float*)d_in[8];
  const float* seg_b = (const float*)d_in[9];
  const float* so_w = (const float*)d_in[10];
  const float* so_b = (const float*)d_in[11];
  const float* sp_wa = (const float*)d_in[12];
  const float* sp_ba = (const float*)d_in[13];
  const float* sp_wb = (const float*)d_in[14];
  const float* sp_bb = (const float*)d_in[15];
  const float* sp_sw = (const float*)d_in[16];
  const float* sp_sb = (const float*)d_in[17];
  const float* fpar = (const float*)d_in[18];

  float* ws = (float*)d_ws;
  float* x_t = ws;                        // 991232 f
  float* a_sm = x_t + 991232;             // 6144 f
  float* fpart0 = a_sm + 6144;            // 8*F_SLICE f
  float* fpart1 = fpart0 + 8 * F_SLICE;   // 8*F_SLICE f
  float* fpart2 = fpart1 + 8 * F_SLICE;   // 8*F_SLICE f
  float* sp_sd = fpart2 + 8 * F_SLICE;    // 5120 f
  float* sa_sd = sp_sd + 5120;            // 5120 f
  float* wrep2d = sa_sd + 5120;           // 4608 f
  unsigned short* pk1h = (unsigned short*)(wrep2d + 4608);
  unsigned short* pk1l = pk1h + PKE;
  unsigned short* pk2h = pk1l + PKE;
  unsigned short* pk2l = pk2h + PKE;
  unsigned short* arep = pk2l + PKE;      // 2*AREP_CV u16
  unsigned short* arep1 = arep + 2 * AREP_CV;  // 3072 u16
  unsigned short* zpage = arep1 + 3072;   // 1024 u16 (zeroed every launch)
  // xpad planes overlay fpart1/fpart2 (prep writes, conv1_mfma reads;
  // fpart1/fpart2 are written only afterwards by conv_mfma #1/#2)
  unsigned short* xpadh = (unsigned short*)fpart1;  // XPADE u16
  unsigned short* xpadl = xpadh + XPADE;            // XPADE u16

  prep_kernel<<<495, 256, 0, stream>>>(x, cpr_w, w3d1, w2d45, w3d23, x_t,
                                       a_sm, wrep2d, arep, arep1, xpadh,
                                       xpadl, zpage);

  conv1_mfma_kernel<<<dim3(6, 4, 64), 512, 0, stream>>>(
      xpadh, xpadl, arep1, b3d1, a_sm, pk1h, pk1l, fpart0);
  conv_mfma_kernel<true><<<dim3(6, 8, 64), 512, 0, stream>>>(
      pk1h, pk1l, arep, b3d23, a_sm + 2048, zpage, pk2h, pk2l, fpart1);
  conv_mfma_kernel<false><<<dim3(6, 8, 64), 512, 0, stream>>>(
      pk2h, pk2l, arep + AREP_CV, b3d23 + 16, a_sm + 4096, zpage, nullptr,
      nullptr, fpart2);

  sp_prep_kernel<<<dim3(64, 5), 256, 0, stream>>>(
      fpart0, fpart1, fpart2, x_t, wrep2d, b2d45, seg_w, seg_b, so_w, so_b,
      sp_wa, sp_ba, sp_wb, sp_bb, sp_sw, sp_sb, sa_sd, sp_sd);
  fuse_kernel<<<4, 256, 0, stream>>>(sa_sd, sp_sd, fpar, (float*)d_out);
}